// Round 10
// baseline (412.610 us; speedup 1.0000x reference)
//
#include <hip/hip_runtime.h>
#include <hip/hip_fp16.h>
#include <math.h>

// Geometry (fixed): B=16, C=1, H=W=1024, f32.
#define H_IMG 1024
#define W_IMG 1024
#define N_B   16
#define NPIX  (H_IMG * W_IMG)
#define N_TOT (16LL * NPIX)

// 64x64 owned tile, halo 12 (11 fused erode iters + 1 dilate ring).
// f16 path (even fid): fp16 LDS + packed-f16 math, r8's verified 2-barrier
// schedule + register-carried er_k[owned] (dilate's mid rows ARE next iter's
// er values -> no LDS re-read). Bool path (odd fid): exact bit-packed Boolean
// morphology of the binary target (verified r8). Block types INTERLEAVED via
// fid parity so both pipe mixes are co-resident per CU.
#define TILE 64
#define HALO 12
#define RG   88          // TILE + 2*HALO rows / data cols
#define HST  92          // f16 LDS row stride in halfs (184 B)
#define SLOTS 32         // atomic accumulator slots (each its own 64B line)

#define PK_NINF 0xFC00FC00u   // {-inf,-inf} f16x2
#define PK_SGN  0x80008000u   // packed sign-flip mask

__device__ __forceinline__ float sigm(float x)  { return 1.0f / (1.0f + __expf(-x)); }

// ---- packed f16 reg ops (pure VALU, no memory: asm ordering is safe) ----
__device__ __forceinline__ unsigned pk_min(unsigned a, unsigned b) {
    unsigned r; asm("v_pk_min_f16 %0, %1, %2" : "=v"(r) : "v"(a), "v"(b)); return r;
}
__device__ __forceinline__ unsigned pk_max(unsigned a, unsigned b) {
    unsigned r; asm("v_pk_max_f16 %0, %1, %2" : "=v"(r) : "v"(a), "v"(b)); return r;
}
__device__ __forceinline__ unsigned pk_add(unsigned a, unsigned b) {
    unsigned r; asm("v_pk_add_f16 %0, %1, %2" : "=v"(r) : "v"(a), "v"(b)); return r;
}
__device__ __forceinline__ unsigned pk_fma(unsigned a, unsigned b, unsigned c) {
    unsigned r; asm("v_pk_fma_f16 %0, %1, %2, %3" : "=v"(r) : "v"(a), "v"(b), "v"(c)); return r;
}
// {hi.low16, lo.high16}: result low half = lo's HIGH half, high half = hi's LOW half.
__device__ __forceinline__ unsigned alignb(unsigned hi, unsigned lo) {
    unsigned r; asm("v_alignbit_b32 %0, %1, %2, 16" : "=v"(r) : "v"(hi), "v"(lo)); return r;
}

union H2U { __half2 h; unsigned u; };

__device__ __forceinline__ uint2 ld2u(const __half* p) { return *(const uint2*)p; }
__device__ __forceinline__ void  st2u(__half* p, unsigned a, unsigned b) { *(uint2*)p = make_uint2(a, b); }
__device__ __forceinline__ void st4h(__half* p, float x, float y, float z, float w) {
    H2U a, b;
    a.h = __floats2half2_rn(x, y);
    b.h = __floats2half2_rn(z, w);
    *(uint2*)p = make_uint2(a.u, b.u);
}

// Overwrite region cells whose GLOBAL coords are outside the image with +INF
// (erode-input identity). b16 stores, consecutive addresses: conflict-free.
__device__ __forceinline__ void band_fix_inf(__half* b, int r0, int c0, int tid)
{
    unsigned short* u = (unsigned short*)b;
    const unsigned short val = 0x7C00;   // +inf f16
    if (r0 == 0) {
        for (int idx = tid; idx < HALO * RG; idx += 512) {
            const int r = idx / RG, c = idx - r * RG;
            u[r * HST + c] = val;
        }
    }
    if (r0 == H_IMG - TILE) {
        for (int idx = tid; idx < HALO * RG; idx += 512) {
            const int r = idx / RG, c = idx - r * RG;
            u[(RG - HALO + r) * HST + c] = val;
        }
    }
    if (c0 == 0) {
        for (int idx = tid; idx < RG * HALO; idx += 512) {
            const int r = idx / HALO, c = idx - r * HALO;
            u[r * HST + c] = val;
        }
    }
    if (c0 == W_IMG - TILE) {
        for (int idx = tid; idx < RG * HALO; idx += 512) {
            const int r = idx / HALO, c = idx - r * HALO;
            u[r * HST + (RG - HALO + c)] = val;
        }
    }
}

// ---------------------------------------------------------------------------
// One erode pass er_k(cur) -> er_{k+1}(nxt), rows [k+1, 87-k), trimmed strips.
// Bank design: b64 strip ops = 1 row x {16,8} consecutive strips per lane
// group (2-way, free); horizontal neighbors via __shfl + v_alignbit; strip-
// boundary lanes fall back to scalar u16 LDS reads (distinct rows -> banks).
// ---------------------------------------------------------------------------
template<bool EDGE>
__device__ __forceinline__
void erode_step(const __half* cur, __half* nxt, int k, int r0, int c0, int tid)
{
    const int rlo = k + 1, rhi = RG - 1 - k;        // rows [rlo, rhi)
    const int sA = rlo >> 2, sE = (rhi + 3) >> 2;   // strips [sA, sE)

    // ---- phase A: strips sA..sA+15 (1 row x 16 strips/quarter) ----
    {
        const int l  = tid & 15;
        const int st = sA + l;
        const int c  = 4 * st;
        bool cOOB = false;
        if (EDGE) {
            const int gcb = c0 - HALO + c;
            cOOB = ((unsigned)gcb > (unsigned)(W_IMG - 4));
        }
        for (int r = rlo + (tid >> 4); r < rhi; r += 32) {
            const int base = r * HST + c;
            const uint2 mid = ld2u(&cur[base]);
            const uint2 up  = ld2u(&cur[base - HST]);
            const uint2 dn  = ld2u(&cur[base + HST]);
            unsigned lfreg = (unsigned)__shfl_up((int)mid.y, 1);    // left strip m23
            unsigned rtreg = (unsigned)__shfl_down((int)mid.x, 1);  // right strip m01
            if (l == 0)  lfreg = ((unsigned)*(const unsigned short*)(cur + base - 1)) << 16;
            if (l == 15) rtreg = (unsigned)*(const unsigned short*)(cur + base + 4);
            const unsigned L01 = alignb(mid.x, lfreg);   // [m-1, m0]
            const unsigned L23 = alignb(mid.y, mid.x);   // [m1 , m2] (== R01)
            const unsigned R23 = alignb(rtreg, mid.y);   // [m3 , m4]
            unsigned e01 = pk_min(pk_min(pk_min(up.x, dn.x), mid.x), pk_min(L01, L23));
            unsigned e23 = pk_min(pk_min(pk_min(up.y, dn.y), mid.y), pk_min(L23, R23));
            if (EDGE) {
                const int gr = r0 - HALO + r;
                if (((unsigned)gr >= (unsigned)H_IMG) | cOOB) { e01 = PK_NINF; e23 = PK_NINF; }
            }
            st2u(&nxt[base], e01, e23);
        }
    }
    // ---- phase B: strips sA+16..sE-1 (2 rows x 8 strips/quarter) ----
    {
        const int l  = tid & 7;
        const int st = sA + 16 + l;
        if (st < sE) {
            const int c = 4 * st;
            bool cOOB = false;
            if (EDGE) {
                const int gcb = c0 - HALO + c;
                cOOB = ((unsigned)gcb > (unsigned)(W_IMG - 4));
            }
            const bool lastS = (st == sE - 1);
            for (int r = rlo + (tid >> 3); r < rhi; r += 64) {
                const int base = r * HST + c;
                const uint2 mid = ld2u(&cur[base]);
                const uint2 up  = ld2u(&cur[base - HST]);
                const uint2 dn  = ld2u(&cur[base + HST]);
                unsigned lfreg = (unsigned)__shfl_up((int)mid.y, 1);
                unsigned rtreg = (unsigned)__shfl_down((int)mid.x, 1);
                if (l == 0)  lfreg = ((unsigned)*(const unsigned short*)(cur + base - 1)) << 16;
                if (lastS)   rtreg = (unsigned)*(const unsigned short*)(cur + base + 4);
                const unsigned L01 = alignb(mid.x, lfreg);
                const unsigned L23 = alignb(mid.y, mid.x);
                const unsigned R23 = alignb(rtreg, mid.y);
                unsigned e01 = pk_min(pk_min(pk_min(up.x, dn.x), mid.x), pk_min(L01, L23));
                unsigned e23 = pk_min(pk_min(pk_min(up.y, dn.y), mid.y), pk_min(L23, R23));
                if (EDGE) {
                    const int gr = r0 - HALO + r;
                    if (((unsigned)gr >= (unsigned)H_IMG) | cOOB) { e01 = PK_NINF; e23 = PK_NINF; }
                }
                st2u(&nxt[base], e01, e23);
            }
        }
    }
}

// ---------------------------------------------------------------------------
// Dilate-open of `buf` at this thread's owned strips (separable V/H, packed).
// Returns open values and the owned mid rows (m0,m1) for register carry.
// ---------------------------------------------------------------------------
struct OpenV { unsigned oA01, oA23, oB01, oB23; uint2 m0, m1; };

__device__ __forceinline__
OpenV dilate_open(const __half* buf, int bA, int bB, int j)
{
    OpenV R;
    const uint2 a0 = ld2u(&buf[bA - HST]);
    R.m0           = ld2u(&buf[bA]);
    const uint2 d0 = ld2u(&buf[bA + HST]);
    const uint2 a1 = ld2u(&buf[bB - HST]);
    R.m1           = ld2u(&buf[bB]);
    const uint2 d1 = ld2u(&buf[bB + HST]);
    const unsigned VA01 = pk_max(pk_max(a0.x, R.m0.x), d0.x);
    const unsigned VA23 = pk_max(pk_max(a0.y, R.m0.y), d0.y);
    const unsigned VB01 = pk_max(pk_max(a1.x, R.m1.x), d1.x);
    const unsigned VB23 = pk_max(pk_max(a1.y, R.m1.y), d1.y);
    // horizontal neighbor regs (hi/lo halves used via alignb)
    unsigned vlA = (unsigned)__shfl_up((int)VA23, 1);        // high = V[cA-1]
    const unsigned vrAa = (unsigned)__shfl_down((int)VA01, 1);
    const unsigned vrAb = (unsigned)__shfl_up((int)VB01, 7); // j==7 seam: strip 8
    unsigned vrA = (j == 7) ? vrAb : vrAa;                   // low = V[cA+4]
    const unsigned vlBa = (unsigned)__shfl_up((int)VB23, 1);
    const unsigned vlBb = (unsigned)__shfl_down((int)VA23, 7); // j==0 seam: strip 7
    unsigned vlB = (j == 0) ? vlBb : vlBa;                   // high = V[cB-1]
    unsigned vrB = (unsigned)__shfl_down((int)VB01, 1);      // low = V[cB+4]
    if (j == 0) {   // block-left halo col: scalar u16 vertical max
        const unsigned t1 = *(const unsigned short*)(buf + bA - HST - 1);
        const unsigned t2 = *(const unsigned short*)(buf + bA - 1);
        const unsigned t3 = *(const unsigned short*)(buf + bA + HST - 1);
        vlA = pk_max(pk_max(t1, t2), t3) << 16;              // value -> high half
    }
    if (j == 7) {   // block-right halo col
        const unsigned t1 = *(const unsigned short*)(buf + bB - HST + 4);
        const unsigned t2 = *(const unsigned short*)(buf + bB + 4);
        const unsigned t3 = *(const unsigned short*)(buf + bB + HST + 4);
        vrB = pk_max(pk_max(t1, t2), t3);                    // value in low half
    }
    const unsigned LA = alignb(VA01, vlA);    // [V-1, V0]
    const unsigned MA = alignb(VA23, VA01);   // [V1 , V2]
    const unsigned RA = alignb(vrA,  VA23);   // [V3 , V4]
    R.oA01 = pk_max(pk_max(LA, MA), VA01);
    R.oA23 = pk_max(pk_max(MA, RA), VA23);
    const unsigned LB = alignb(VB01, vlB);
    const unsigned MB = alignb(VB23, VB01);
    const unsigned RB = alignb(vrB,  VB23);
    R.oB01 = pk_max(pk_max(LB, MB), VB01);
    R.oB23 = pk_max(pk_max(MB, RB), VB23);
    return R;
}

// delta = relu(e - open); skel += relu(delta - skel*delta)   (packed f16)
__device__ __forceinline__ void skel_upd(unsigned& sk, unsigned e, unsigned o)
{
    const unsigned d = pk_max(pk_add(e, o ^ PK_SGN), 0u);
    const unsigned u = pk_max(pk_fma(sk ^ PK_SGN, d, d), 0u);
    sk = pk_add(sk, u);
}

// ---------------------------------------------------------------------------
// f16 path: whole soft_skeleton of sigmoid(pred), fused BCE/dice + skel
// reductions. r8's 2-barrier schedule; er_k[owned] carried in registers
// (initial read after load barrier; thereafter dilate's m0/m1 = er_{k+1}).
// ---------------------------------------------------------------------------
__device__ __forceinline__
void skel_f16(const float* __restrict__ pred, const float* __restrict__ tgt,
              double* __restrict__ acc, __half* cur, __half* nxt, float* red,
              int z, int r0, int c0, int tid, int bid)
{
    const float* s = pred + (size_t)z * NPIX;

    // ---- load 88x88 region (+4-col pad), phase-aligned, sigmoid applied ----
    {   // phase A: strips 0..15, 1 row x 16 strips per quarter-wave
        const int st = tid & 15, c = 4 * st;
        const int gc = c0 - HALO + c;
        const bool vec = (gc >= 0) && (gc + 3 < W_IMG);
        for (int r = tid >> 4; r < RG; r += 32) {
            const int gr = min(max(r0 - HALO + r, 0), H_IMG - 1);
            const float* row = s + (size_t)gr * W_IMG;
            float4 v;
            if (vec) v = *(const float4*)&row[gc];
            else {
                v.x = row[min(max(gc + 0, 0), W_IMG - 1)];
                v.y = row[min(max(gc + 1, 0), W_IMG - 1)];
                v.z = row[min(max(gc + 2, 0), W_IMG - 1)];
                v.w = row[min(max(gc + 3, 0), W_IMG - 1)];
            }
            st4h(&cur[r * HST + c], sigm(v.x), sigm(v.y), sigm(v.z), sigm(v.w));
        }
    }
    {   // phase B: strips 16..22 (incl pad strip 22), 2 rows x 8 strips
        const int st = 16 + (tid & 7);
        if (st < 23) {
            const int c = 4 * st, gc = c0 - HALO + c;
            const bool vec = (gc >= 0) && (gc + 3 < W_IMG);
            for (int r = tid >> 3; r < RG; r += 64) {
                const int gr = min(max(r0 - HALO + r, 0), H_IMG - 1);
                const float* row = s + (size_t)gr * W_IMG;
                float4 v;
                if (vec) v = *(const float4*)&row[gc];
                else {
                    v.x = row[min(max(gc + 0, 0), W_IMG - 1)];
                    v.y = row[min(max(gc + 1, 0), W_IMG - 1)];
                    v.z = row[min(max(gc + 2, 0), W_IMG - 1)];
                    v.w = row[min(max(gc + 3, 0), W_IMG - 1)];
                }
                st4h(&cur[r * HST + c], sigm(v.x), sigm(v.y), sigm(v.z), sigm(v.w));
            }
        }
    }
    __syncthreads();

    const bool edge = (r0 == 0) | (c0 == 0) | (r0 == H_IMG - TILE) | (c0 == W_IMG - TILE);

    unsigned skA01 = 0, skA23 = 0, skB01 = 0, skB23 = 0;

    const int oy = tid >> 3;      // owned row 0..63
    const int j  = tid & 7;       // strip slot (strips j, j+8 of owned)
    const int rr = HALO + oy;
    const int bA = rr * HST + HALO + 4 * j;
    const int bB = bA + 32;

    // er_0[owned] -> registers (band_fix never touches owned cells)
    uint2 eA = ld2u(&cur[bA]);
    uint2 eB = ld2u(&cur[bB]);

    if (!edge) {
        // ===== interior: r8's 2-barrier schedule + register carry =====
        #pragma unroll 1
        for (int k = 0; k <= 10; ++k) {
            erode_step<false>(cur, nxt, k, r0, c0, tid);
            __syncthreads();
            const OpenV R = dilate_open(nxt, bA, bB, j);   // open_k = dilate(er_{k+1})
            skel_upd(skA01, eA.x, R.oA01);
            skel_upd(skA23, eA.y, R.oA23);
            skel_upd(skB01, eB.x, R.oB01);
            skel_upd(skB23, eB.y, R.oB23);
            eA = R.m0; eB = R.m1;                          // er_{k+1}[owned], free
            __syncthreads();
            __half* tp = cur; cur = nxt; nxt = tp;
        }
    } else {
        // ===== edge blocks: verified 3-barrier path + register carry =====
        #pragma unroll 1
        for (int k = 0; k <= 10; ++k) {
            band_fix_inf(cur, r0, c0, tid);
            __syncthreads();
            erode_step<true>(cur, nxt, k, r0, c0, tid);
            __syncthreads();
            const OpenV R = dilate_open(nxt, bA, bB, j);   // dilate(er_{k+1})
            skel_upd(skA01, eA.x, R.oA01);
            skel_upd(skA23, eA.y, R.oA23);
            skel_upd(skB01, eB.x, R.oB01);
            skel_upd(skB23, eB.y, R.oB23);
            eA = R.m0; eB = R.m1;
            __syncthreads();
            __half* tp = cur; cur = nxt; nxt = tp;
        }
    }

    // ---- unpack skel to f32 ----
    float skf[8];
    {
        H2U u; float2 f;
        u.u = skA01; f = __half22float2(u.h); skf[0] = f.x; skf[1] = f.y;
        u.u = skA23; f = __half22float2(u.h); skf[2] = f.x; skf[3] = f.y;
        u.u = skB01; f = __half22float2(u.h); skf[4] = f.x; skf[5] = f.y;
        u.u = skB23; f = __half22float2(u.h); skf[6] = f.x; skf[7] = f.y;
    }

    // ---- fused reductions over owned pixels: skel sums + BCE/dice ----
    const size_t gbase = (size_t)z * NPIX + (size_t)(r0 + oy) * W_IMG + c0;
    const float* op = tgt  + gbase;
    const float* pp = pred + gbase;
    float ss = 0.f, sso = 0.f, sb = 0.f, sp = 0.f, sy = 0.f, spy = 0.f;
    #pragma unroll
    for (int t = 0; t < 2; ++t) {
        const int cc = 4 * (j + 8 * t);
        const float4 ov = *(const float4*)&op[cc];
        const float o0 = ov.x, o1 = ov.y, o2 = ov.z, o3 = ov.w;   // raw target
        const float s0 = skf[4*t], s1 = skf[4*t+1], s2 = skf[4*t+2], s3 = skf[4*t+3];
        ss  += s0 + s1 + s2 + s3;
        sso += s0 * o0 + s1 * o1 + s2 * o2 + s3 * o3;
        const float4 xv = *(const float4*)&pp[cc];
        const float xs[4] = {xv.x, xv.y, xv.z, xv.w};
        const float ys[4] = {o0, o1, o2, o3};
        #pragma unroll
        for (int q = 0; q < 4; ++q) {
            const float x = xs[q], y = ys[q];
            const float zz = __expf(-fabsf(x));
            const float inv = 1.0f / (1.0f + zz);
            sb += fmaxf(x, 0.f) + __logf(1.0f + zz) - y * x;
            const float p = (x >= 0.f) ? inv : zz * inv;
            sp += p; sy += y; spy += p * y;
        }
    }
    for (int off = 32; off > 0; off >>= 1) {
        ss  += __shfl_down(ss,  off);
        sso += __shfl_down(sso, off);
        sb  += __shfl_down(sb,  off);
        sp  += __shfl_down(sp,  off);
        sy  += __shfl_down(sy,  off);
        spy += __shfl_down(spy, off);
    }
    const int wid = tid >> 6, lane = tid & 63;
    if (lane == 0) {
        red[0 * 8 + wid] = ss;  red[1 * 8 + wid] = sso;
        red[2 * 8 + wid] = sb;  red[3 * 8 + wid] = sp;
        red[4 * 8 + wid] = sy;  red[5 * 8 + wid] = spy;
    }
    __syncthreads();
    if (tid == 0) {
        double SS = 0, SO = 0, B0 = 0, B1 = 0, B2 = 0, B3 = 0;
        for (int w = 0; w < 8; ++w) {
            SS += (double)red[0 * 8 + w];  SO += (double)red[1 * 8 + w];
            B0 += (double)red[2 * 8 + w];  B1 += (double)red[3 * 8 + w];
            B2 += (double)red[4 * 8 + w];  B3 += (double)red[5 * 8 + w];
        }
        const int slot = bid & (SLOTS - 1);
        atomicAdd(&acc[slot * 8 + 4], SS);
        atomicAdd(&acc[slot * 8 + 5], SO);
        atomicAdd(&acc[slot * 8 + 0], B0);
        atomicAdd(&acc[slot * 8 + 1], B1);
        atomicAdd(&acc[slot * 8 + 2], B2);
        atomicAdd(&acc[slot * 8 + 3], B3);
    }
}

// ---------------------------------------------------------------------------
// Bool path: EXACT bit-packed skeleton of the binary target (verified r8).
// ---------------------------------------------------------------------------
__device__ __forceinline__
void bool_core(const float* __restrict__ tgt, const float* __restrict__ pred,
               double* __restrict__ acc, unsigned* bb, float* red,
               int z, int r0, int c0, int tid, int bid)
{
    unsigned* A  = bb;              // [RG*4]
    unsigned* B  = bb + RG * 4;
    unsigned* SK = bb + RG * 8;
    const float* tz = tgt + (size_t)z * NPIX;

    // ---- load + pack bits via wave ballot (row-major, 64+24 cols) ----
    {
        const int wv = tid >> 6, ln = tid & 63;
        for (int r = wv; r < RG; r += 8) {
            const int gr = min(max(r0 - HALO + r, 0), H_IMG - 1);
            const float* row = tz + (size_t)gr * W_IMG;
            const int gc = c0 - HALO + ln;
            const float v = row[min(max(gc, 0), W_IMG - 1)];
            const unsigned long long b0 = __ballot(v > 0.5f);
            float v2 = 0.f;
            if (ln < 24) v2 = row[min(max(gc + 64, 0), W_IMG - 1)];
            const unsigned long long b1 = __ballot((ln < 24) && (v2 > 0.5f));
            if (ln < 4) {
                const unsigned val = (ln == 0) ? (unsigned)b0
                                   : (ln == 1) ? (unsigned)(b0 >> 32)
                                   : (ln == 2) ? (unsigned)b1 : 0u;
                A[r * 4 + ln] = val;
            }
        }
    }
    __syncthreads();

    const int r = tid >> 2, w = tid & 3;
    const bool act = (tid < RG * 4);

    // out-of-image masks (1 = outside image)
    const int gcb = c0 - HALO + 32 * w;
    unsigned cm = 0;
    {
        const int lo = -gcb;
        if (lo > 0) cm |= (lo >= 32) ? 0xFFFFFFFFu : ((1u << lo) - 1u);
        const int hs = W_IMG - gcb;
        if (hs < 32) cm |= (hs <= 0) ? 0xFFFFFFFFu : ~((1u << hs) - 1u);
    }
    const int grs = r0 - HALO + r;
    const unsigned Mself = cm | ((((unsigned)grs)       >= (unsigned)H_IMG) ? 0xFFFFFFFFu : 0u);
    const unsigned Mup   = cm | ((((unsigned)(grs - 1)) >= (unsigned)H_IMG) ? 0xFFFFFFFFu : 0u);
    const unsigned Mdn   = cm | ((((unsigned)(grs + 1)) >= (unsigned)H_IMG) ? 0xFFFFFFFFu : 0u);
    const unsigned KILL  = ~Mself;

    const int iu = max(r - 1, 0) * 4 + w;
    const int id = min(r + 1, RG - 1) * 4 + w;

    unsigned mid  = act ? A[r * 4 + w] : 0u;
    unsigned skel = 0u;
    unsigned* sB = A; unsigned* dB = B;

    for (int k = 0; k < 11; ++k) {
        const unsigned me = mid | Mself;
        unsigned up = 0xFFFFFFFFu, dn = 0xFFFFFFFFu;
        if (act) { up = sB[iu] | Mup; dn = sB[id] | Mdn; }
        const unsigned pv = (unsigned)__shfl_up((int)me, 1);
        const unsigned nx = (unsigned)__shfl_down((int)me, 1);
        const unsigned Lh = (me << 1) | (pv >> 31);
        const unsigned Rh = (me >> 1) | (nx << 31);
        const unsigned e  = (me & up & dn & Lh & Rh) & KILL;
        if (act) dB[r * 4 + w] = e;
        __syncthreads();
        unsigned eu = 0, ed = 0;
        if (act) { eu = dB[iu]; ed = dB[id]; }
        const unsigned V  = e | eu | ed;
        const unsigned pV = (unsigned)__shfl_up((int)V, 1);
        const unsigned nV = (unsigned)__shfl_down((int)V, 1);
        const unsigned open = V | ((V << 1) | (pV >> 31)) | ((V >> 1) | (nV << 31));
        skel |= mid & ~open;
        mid = e;
        unsigned* tp = sB; sB = dB; dB = tp;
    }
    if (act) SK[r * 4 + w] = skel;
    __syncthreads();

    // ---- epilogue: ss = sum(skel bits), sso = sum(skel * sigmoid(pred)) ----
    const int oy = tid >> 3, j = tid & 7;
    const size_t gbase = (size_t)z * NPIX + (size_t)(r0 + oy) * W_IMG + c0;
    const float* pp = pred + gbase;
    float ss = 0.f, sso = 0.f;
    #pragma unroll
    for (int t = 0; t < 2; ++t) {
        const int cc  = 4 * (j + 8 * t);
        const int rcb = HALO + cc;
        const unsigned wd = SK[(HALO + oy) * 4 + (rcb >> 5)] >> (rcb & 31);
        const float4 xv = *(const float4*)&pp[cc];
        const float p0 = sigm(xv.x), p1 = sigm(xv.y), p2 = sigm(xv.z), p3 = sigm(xv.w);
        const float b0 = (float)( wd       & 1u);
        const float b1 = (float)((wd >> 1) & 1u);
        const float b2 = (float)((wd >> 2) & 1u);
        const float b3 = (float)((wd >> 3) & 1u);
        ss  += b0 + b1 + b2 + b3;
        sso += b0 * p0 + b1 * p1 + b2 * p2 + b3 * p3;
    }
    for (int off = 32; off > 0; off >>= 1) {
        ss  += __shfl_down(ss,  off);
        sso += __shfl_down(sso, off);
    }
    const int wid = tid >> 6, lane = tid & 63;
    if (lane == 0) { red[0 * 8 + wid] = ss; red[1 * 8 + wid] = sso; }
    __syncthreads();
    if (tid == 0) {
        double SS = 0, SO = 0;
        for (int wq = 0; wq < 8; ++wq) { SS += (double)red[0 * 8 + wq]; SO += (double)red[1 * 8 + wq]; }
        const int slot = bid & (SLOTS - 1);
        atomicAdd(&acc[slot * 8 + 6], SS);
        atomicAdd(&acc[slot * 8 + 7], SO);
    }
}

// One dispatch, type-INTERLEAVED: consecutive flat block ids alternate
// {f16 skel(sigmoid(pred)) + BCE/dice} and {bit-packed skel(target)} on the
// SAME tile -> both pipe mixes co-resident per CU, L2-friendly.
__global__ __launch_bounds__(512, 8)
void skel_all(const float* __restrict__ pred, const float* __restrict__ tgt,
              double* __restrict__ acc)
{
    __shared__ __align__(16) __half buf0[RG * HST];
    __shared__ __align__(16) __half buf1[RG * HST];
    __shared__ float red[48];
    const int tid = threadIdx.x;
    const int fid = ((int)blockIdx.z * (int)gridDim.y + (int)blockIdx.y) * (int)gridDim.x
                    + (int)blockIdx.x;            // 0..8191, x fastest
    const int tile = fid >> 1;                    // 0..4095
    const int x = tile & 15, y = (tile >> 4) & 15, z = tile >> 8;
    const int r0 = y * TILE, c0 = x * TILE;
    if ((fid & 1) == 0)
        skel_f16(pred, tgt, acc, buf0, buf1, red, z, r0, c0, tid, tile);
    else
        bool_core(tgt, pred, acc, (unsigned*)buf0, red, z, r0, c0, tid, tile);
}

__global__ void zero_acc(double* acc) { acc[threadIdx.x] = 0.0; }

__global__ void finalize_k(const double* __restrict__ acc, float* __restrict__ out)
{
    __shared__ double S[8];
    const int jj = threadIdx.x;
    if (jj < 8) {
        double t = 0.0;
        for (int s = 0; s < SLOTS; ++s) t += acc[s * 8 + jj];
        S[jj] = t;
    }
    __syncthreads();
    if (jj == 0) {
        const double bce   = S[0] / (double)N_TOT;
        const double dice  = (2.0 * S[3] + 1.0) / (S[1] + S[2] + 1.0);
        const double tprec = (S[5] + 1.0) / (S[4] + 1.0);
        const double tsens = (S[7] + 1.0) / (S[6] + 1.0);
        const double cl    = 2.0 * tprec * tsens / (tprec + tsens + 1e-7);
        out[0] = (float)(0.3 * bce + 0.3 * (1.0 - dice) + 0.4 * (1.0 - cl));
    }
}

// ---------------------------------------------------------------------------
extern "C" void kernel_launch(void* const* d_in, const int* in_sizes, int n_in,
                              void* d_out, int out_size, void* d_ws, size_t ws_size,
                              hipStream_t stream)
{
    const float* pred = (const float*)d_in[0];
    const float* tgt  = (const float*)d_in[1];
    float* out = (float*)d_out;
    double* acc = (double*)d_ws;                  // SLOTS*8 doubles = 2 KB

    zero_acc<<<1, SLOTS * 8, 0, stream>>>(acc);

    const dim3 grid(16, 16, 32);                  // 8192 blocks, fid-interleaved
    skel_all<<<grid, 512, 0, stream>>>(pred, tgt, acc);

    finalize_k<<<1, 64, 0, stream>>>(acc, out);
}

// Round 11
// 406.533 us; speedup vs baseline: 1.0149x; 1.0149x over previous
//
#include <hip/hip_runtime.h>
#include <hip/hip_fp16.h>
#include <math.h>

// Geometry (fixed): B=16, C=1, H=W=1024, f32.
#define H_IMG 1024
#define W_IMG 1024
#define N_B   16
#define NPIX  (H_IMG * W_IMG)
#define N_TOT (16LL * NPIX)

// 64x64 owned tile, halo 12 (11 fused erode iters + 1 dilate ring).
// f16 path: fp16 LDS + packed-f16 math, r8's verified 2-barrier schedule +
// register-carried er_k[owned]. Bool path: exact bit-packed Boolean
// morphology of the binary target (verified r8).
// Block types interleaved in GROUPS OF 8 consecutive fids: workgroup->XCD
// assignment round-robins consecutive ids across the 8 XCDs, so an 8-block
// group of one type covers all XCDs (r10's fid&1 split aliased with XCD
// parity and halved machine utilization -- lesson learned).
#define TILE 64
#define HALO 12
#define RG   88          // TILE + 2*HALO rows / data cols
#define HST  92          // f16 LDS row stride in halfs (184 B)
#define SLOTS 32         // atomic accumulator slots (each its own 64B line)

#define PK_NINF 0xFC00FC00u   // {-inf,-inf} f16x2
#define PK_SGN  0x80008000u   // packed sign-flip mask

__device__ __forceinline__ float sigm(float x)  { return 1.0f / (1.0f + __expf(-x)); }

// ---- packed f16 reg ops (pure VALU, no memory: asm ordering is safe) ----
__device__ __forceinline__ unsigned pk_min(unsigned a, unsigned b) {
    unsigned r; asm("v_pk_min_f16 %0, %1, %2" : "=v"(r) : "v"(a), "v"(b)); return r;
}
__device__ __forceinline__ unsigned pk_max(unsigned a, unsigned b) {
    unsigned r; asm("v_pk_max_f16 %0, %1, %2" : "=v"(r) : "v"(a), "v"(b)); return r;
}
__device__ __forceinline__ unsigned pk_add(unsigned a, unsigned b) {
    unsigned r; asm("v_pk_add_f16 %0, %1, %2" : "=v"(r) : "v"(a), "v"(b)); return r;
}
__device__ __forceinline__ unsigned pk_fma(unsigned a, unsigned b, unsigned c) {
    unsigned r; asm("v_pk_fma_f16 %0, %1, %2, %3" : "=v"(r) : "v"(a), "v"(b), "v"(c)); return r;
}
// {hi.low16, lo.high16}: result low half = lo's HIGH half, high half = hi's LOW half.
__device__ __forceinline__ unsigned alignb(unsigned hi, unsigned lo) {
    unsigned r; asm("v_alignbit_b32 %0, %1, %2, 16" : "=v"(r) : "v"(hi), "v"(lo)); return r;
}

union H2U { __half2 h; unsigned u; };

__device__ __forceinline__ uint2 ld2u(const __half* p) { return *(const uint2*)p; }
__device__ __forceinline__ void  st2u(__half* p, unsigned a, unsigned b) { *(uint2*)p = make_uint2(a, b); }
__device__ __forceinline__ void st4h(__half* p, float x, float y, float z, float w) {
    H2U a, b;
    a.h = __floats2half2_rn(x, y);
    b.h = __floats2half2_rn(z, w);
    *(uint2*)p = make_uint2(a.u, b.u);
}

// Overwrite region cells whose GLOBAL coords are outside the image with +INF
// (erode-input identity). b16 stores, consecutive addresses: conflict-free.
__device__ __forceinline__ void band_fix_inf(__half* b, int r0, int c0, int tid)
{
    unsigned short* u = (unsigned short*)b;
    const unsigned short val = 0x7C00;   // +inf f16
    if (r0 == 0) {
        for (int idx = tid; idx < HALO * RG; idx += 512) {
            const int r = idx / RG, c = idx - r * RG;
            u[r * HST + c] = val;
        }
    }
    if (r0 == H_IMG - TILE) {
        for (int idx = tid; idx < HALO * RG; idx += 512) {
            const int r = idx / RG, c = idx - r * RG;
            u[(RG - HALO + r) * HST + c] = val;
        }
    }
    if (c0 == 0) {
        for (int idx = tid; idx < RG * HALO; idx += 512) {
            const int r = idx / HALO, c = idx - r * HALO;
            u[r * HST + c] = val;
        }
    }
    if (c0 == W_IMG - TILE) {
        for (int idx = tid; idx < RG * HALO; idx += 512) {
            const int r = idx / HALO, c = idx - r * HALO;
            u[r * HST + (RG - HALO + c)] = val;
        }
    }
}

// ---------------------------------------------------------------------------
// One erode pass er_k(cur) -> er_{k+1}(nxt), rows [k+1, 87-k), trimmed strips.
// Bank design: b64 strip ops = 1 row x {16,8} consecutive strips per lane
// group (2-way, free); horizontal neighbors via __shfl + v_alignbit; strip-
// boundary lanes fall back to scalar u16 LDS reads (distinct rows -> banks).
// ---------------------------------------------------------------------------
template<bool EDGE>
__device__ __forceinline__
void erode_step(const __half* cur, __half* nxt, int k, int r0, int c0, int tid)
{
    const int rlo = k + 1, rhi = RG - 1 - k;        // rows [rlo, rhi)
    const int sA = rlo >> 2, sE = (rhi + 3) >> 2;   // strips [sA, sE)

    // ---- phase A: strips sA..sA+15 (1 row x 16 strips/quarter) ----
    {
        const int l  = tid & 15;
        const int st = sA + l;
        const int c  = 4 * st;
        bool cOOB = false;
        if (EDGE) {
            const int gcb = c0 - HALO + c;
            cOOB = ((unsigned)gcb > (unsigned)(W_IMG - 4));
        }
        for (int r = rlo + (tid >> 4); r < rhi; r += 32) {
            const int base = r * HST + c;
            const uint2 mid = ld2u(&cur[base]);
            const uint2 up  = ld2u(&cur[base - HST]);
            const uint2 dn  = ld2u(&cur[base + HST]);
            unsigned lfreg = (unsigned)__shfl_up((int)mid.y, 1);    // left strip m23
            unsigned rtreg = (unsigned)__shfl_down((int)mid.x, 1);  // right strip m01
            if (l == 0)  lfreg = ((unsigned)*(const unsigned short*)(cur + base - 1)) << 16;
            if (l == 15) rtreg = (unsigned)*(const unsigned short*)(cur + base + 4);
            const unsigned L01 = alignb(mid.x, lfreg);   // [m-1, m0]
            const unsigned L23 = alignb(mid.y, mid.x);   // [m1 , m2] (== R01)
            const unsigned R23 = alignb(rtreg, mid.y);   // [m3 , m4]
            unsigned e01 = pk_min(pk_min(pk_min(up.x, dn.x), mid.x), pk_min(L01, L23));
            unsigned e23 = pk_min(pk_min(pk_min(up.y, dn.y), mid.y), pk_min(L23, R23));
            if (EDGE) {
                const int gr = r0 - HALO + r;
                if (((unsigned)gr >= (unsigned)H_IMG) | cOOB) { e01 = PK_NINF; e23 = PK_NINF; }
            }
            st2u(&nxt[base], e01, e23);
        }
    }
    // ---- phase B: strips sA+16..sE-1 (2 rows x 8 strips/quarter) ----
    {
        const int l  = tid & 7;
        const int st = sA + 16 + l;
        if (st < sE) {
            const int c = 4 * st;
            bool cOOB = false;
            if (EDGE) {
                const int gcb = c0 - HALO + c;
                cOOB = ((unsigned)gcb > (unsigned)(W_IMG - 4));
            }
            const bool lastS = (st == sE - 1);
            for (int r = rlo + (tid >> 3); r < rhi; r += 64) {
                const int base = r * HST + c;
                const uint2 mid = ld2u(&cur[base]);
                const uint2 up  = ld2u(&cur[base - HST]);
                const uint2 dn  = ld2u(&cur[base + HST]);
                unsigned lfreg = (unsigned)__shfl_up((int)mid.y, 1);
                unsigned rtreg = (unsigned)__shfl_down((int)mid.x, 1);
                if (l == 0)  lfreg = ((unsigned)*(const unsigned short*)(cur + base - 1)) << 16;
                if (lastS)   rtreg = (unsigned)*(const unsigned short*)(cur + base + 4);
                const unsigned L01 = alignb(mid.x, lfreg);
                const unsigned L23 = alignb(mid.y, mid.x);
                const unsigned R23 = alignb(rtreg, mid.y);
                unsigned e01 = pk_min(pk_min(pk_min(up.x, dn.x), mid.x), pk_min(L01, L23));
                unsigned e23 = pk_min(pk_min(pk_min(up.y, dn.y), mid.y), pk_min(L23, R23));
                if (EDGE) {
                    const int gr = r0 - HALO + r;
                    if (((unsigned)gr >= (unsigned)H_IMG) | cOOB) { e01 = PK_NINF; e23 = PK_NINF; }
                }
                st2u(&nxt[base], e01, e23);
            }
        }
    }
}

// ---------------------------------------------------------------------------
// Dilate-open of `buf` at this thread's owned strips (separable V/H, packed).
// Returns open values and the owned mid rows (m0,m1) for register carry.
// ---------------------------------------------------------------------------
struct OpenV { unsigned oA01, oA23, oB01, oB23; uint2 m0, m1; };

__device__ __forceinline__
OpenV dilate_open(const __half* buf, int bA, int bB, int j)
{
    OpenV R;
    const uint2 a0 = ld2u(&buf[bA - HST]);
    R.m0           = ld2u(&buf[bA]);
    const uint2 d0 = ld2u(&buf[bA + HST]);
    const uint2 a1 = ld2u(&buf[bB - HST]);
    R.m1           = ld2u(&buf[bB]);
    const uint2 d1 = ld2u(&buf[bB + HST]);
    const unsigned VA01 = pk_max(pk_max(a0.x, R.m0.x), d0.x);
    const unsigned VA23 = pk_max(pk_max(a0.y, R.m0.y), d0.y);
    const unsigned VB01 = pk_max(pk_max(a1.x, R.m1.x), d1.x);
    const unsigned VB23 = pk_max(pk_max(a1.y, R.m1.y), d1.y);
    // horizontal neighbor regs (hi/lo halves used via alignb)
    unsigned vlA = (unsigned)__shfl_up((int)VA23, 1);        // high = V[cA-1]
    const unsigned vrAa = (unsigned)__shfl_down((int)VA01, 1);
    const unsigned vrAb = (unsigned)__shfl_up((int)VB01, 7); // j==7 seam: strip 8
    unsigned vrA = (j == 7) ? vrAb : vrAa;                   // low = V[cA+4]
    const unsigned vlBa = (unsigned)__shfl_up((int)VB23, 1);
    const unsigned vlBb = (unsigned)__shfl_down((int)VA23, 7); // j==0 seam: strip 7
    unsigned vlB = (j == 0) ? vlBb : vlBa;                   // high = V[cB-1]
    unsigned vrB = (unsigned)__shfl_down((int)VB01, 1);      // low = V[cB+4]
    if (j == 0) {   // block-left halo col: scalar u16 vertical max
        const unsigned t1 = *(const unsigned short*)(buf + bA - HST - 1);
        const unsigned t2 = *(const unsigned short*)(buf + bA - 1);
        const unsigned t3 = *(const unsigned short*)(buf + bA + HST - 1);
        vlA = pk_max(pk_max(t1, t2), t3) << 16;              // value -> high half
    }
    if (j == 7) {   // block-right halo col
        const unsigned t1 = *(const unsigned short*)(buf + bB - HST + 4);
        const unsigned t2 = *(const unsigned short*)(buf + bB + 4);
        const unsigned t3 = *(const unsigned short*)(buf + bB + HST + 4);
        vrB = pk_max(pk_max(t1, t2), t3);                    // value in low half
    }
    const unsigned LA = alignb(VA01, vlA);    // [V-1, V0]
    const unsigned MA = alignb(VA23, VA01);   // [V1 , V2]
    const unsigned RA = alignb(vrA,  VA23);   // [V3 , V4]
    R.oA01 = pk_max(pk_max(LA, MA), VA01);
    R.oA23 = pk_max(pk_max(MA, RA), VA23);
    const unsigned LB = alignb(VB01, vlB);
    const unsigned MB = alignb(VB23, VB01);
    const unsigned RB = alignb(vrB,  VB23);
    R.oB01 = pk_max(pk_max(LB, MB), VB01);
    R.oB23 = pk_max(pk_max(MB, RB), VB23);
    return R;
}

// delta = relu(e - open); skel += relu(delta - skel*delta)   (packed f16)
__device__ __forceinline__ void skel_upd(unsigned& sk, unsigned e, unsigned o)
{
    const unsigned d = pk_max(pk_add(e, o ^ PK_SGN), 0u);
    const unsigned u = pk_max(pk_fma(sk ^ PK_SGN, d, d), 0u);
    sk = pk_add(sk, u);
}

// ---------------------------------------------------------------------------
// f16 path: whole soft_skeleton of sigmoid(pred), fused BCE/dice + skel
// reductions. r8's 2-barrier schedule; er_k[owned] carried in registers.
// ---------------------------------------------------------------------------
__device__ __forceinline__
void skel_f16(const float* __restrict__ pred, const float* __restrict__ tgt,
              double* __restrict__ acc, __half* cur, __half* nxt, float* red,
              int z, int r0, int c0, int tid, int bid)
{
    const float* s = pred + (size_t)z * NPIX;

    // ---- load 88x88 region (+4-col pad), phase-aligned, sigmoid applied ----
    {   // phase A: strips 0..15, 1 row x 16 strips per quarter-wave
        const int st = tid & 15, c = 4 * st;
        const int gc = c0 - HALO + c;
        const bool vec = (gc >= 0) && (gc + 3 < W_IMG);
        for (int r = tid >> 4; r < RG; r += 32) {
            const int gr = min(max(r0 - HALO + r, 0), H_IMG - 1);
            const float* row = s + (size_t)gr * W_IMG;
            float4 v;
            if (vec) v = *(const float4*)&row[gc];
            else {
                v.x = row[min(max(gc + 0, 0), W_IMG - 1)];
                v.y = row[min(max(gc + 1, 0), W_IMG - 1)];
                v.z = row[min(max(gc + 2, 0), W_IMG - 1)];
                v.w = row[min(max(gc + 3, 0), W_IMG - 1)];
            }
            st4h(&cur[r * HST + c], sigm(v.x), sigm(v.y), sigm(v.z), sigm(v.w));
        }
    }
    {   // phase B: strips 16..22 (incl pad strip 22), 2 rows x 8 strips
        const int st = 16 + (tid & 7);
        if (st < 23) {
            const int c = 4 * st, gc = c0 - HALO + c;
            const bool vec = (gc >= 0) && (gc + 3 < W_IMG);
            for (int r = tid >> 3; r < RG; r += 64) {
                const int gr = min(max(r0 - HALO + r, 0), H_IMG - 1);
                const float* row = s + (size_t)gr * W_IMG;
                float4 v;
                if (vec) v = *(const float4*)&row[gc];
                else {
                    v.x = row[min(max(gc + 0, 0), W_IMG - 1)];
                    v.y = row[min(max(gc + 1, 0), W_IMG - 1)];
                    v.z = row[min(max(gc + 2, 0), W_IMG - 1)];
                    v.w = row[min(max(gc + 3, 0), W_IMG - 1)];
                }
                st4h(&cur[r * HST + c], sigm(v.x), sigm(v.y), sigm(v.z), sigm(v.w));
            }
        }
    }
    __syncthreads();

    const bool edge = (r0 == 0) | (c0 == 0) | (r0 == H_IMG - TILE) | (c0 == W_IMG - TILE);

    unsigned skA01 = 0, skA23 = 0, skB01 = 0, skB23 = 0;

    const int oy = tid >> 3;      // owned row 0..63
    const int j  = tid & 7;       // strip slot (strips j, j+8 of owned)
    const int rr = HALO + oy;
    const int bA = rr * HST + HALO + 4 * j;
    const int bB = bA + 32;

    // er_0[owned] -> registers (band_fix never touches owned cells)
    uint2 eA = ld2u(&cur[bA]);
    uint2 eB = ld2u(&cur[bB]);

    if (!edge) {
        // ===== interior: r8's 2-barrier schedule + register carry =====
        #pragma unroll 1
        for (int k = 0; k <= 10; ++k) {
            erode_step<false>(cur, nxt, k, r0, c0, tid);
            __syncthreads();
            const OpenV R = dilate_open(nxt, bA, bB, j);   // open_k = dilate(er_{k+1})
            skel_upd(skA01, eA.x, R.oA01);
            skel_upd(skA23, eA.y, R.oA23);
            skel_upd(skB01, eB.x, R.oB01);
            skel_upd(skB23, eB.y, R.oB23);
            eA = R.m0; eB = R.m1;                          // er_{k+1}[owned], free
            __syncthreads();
            __half* tp = cur; cur = nxt; nxt = tp;
        }
    } else {
        // ===== edge blocks: verified 3-barrier path + register carry =====
        #pragma unroll 1
        for (int k = 0; k <= 10; ++k) {
            band_fix_inf(cur, r0, c0, tid);
            __syncthreads();
            erode_step<true>(cur, nxt, k, r0, c0, tid);
            __syncthreads();
            const OpenV R = dilate_open(nxt, bA, bB, j);   // dilate(er_{k+1})
            skel_upd(skA01, eA.x, R.oA01);
            skel_upd(skA23, eA.y, R.oA23);
            skel_upd(skB01, eB.x, R.oB01);
            skel_upd(skB23, eB.y, R.oB23);
            eA = R.m0; eB = R.m1;
            __syncthreads();
            __half* tp = cur; cur = nxt; nxt = tp;
        }
    }

    // ---- unpack skel to f32 ----
    float skf[8];
    {
        H2U u; float2 f;
        u.u = skA01; f = __half22float2(u.h); skf[0] = f.x; skf[1] = f.y;
        u.u = skA23; f = __half22float2(u.h); skf[2] = f.x; skf[3] = f.y;
        u.u = skB01; f = __half22float2(u.h); skf[4] = f.x; skf[5] = f.y;
        u.u = skB23; f = __half22float2(u.h); skf[6] = f.x; skf[7] = f.y;
    }

    // ---- fused reductions over owned pixels: skel sums + BCE/dice ----
    const size_t gbase = (size_t)z * NPIX + (size_t)(r0 + oy) * W_IMG + c0;
    const float* op = tgt  + gbase;
    const float* pp = pred + gbase;
    float ss = 0.f, sso = 0.f, sb = 0.f, sp = 0.f, sy = 0.f, spy = 0.f;
    #pragma unroll
    for (int t = 0; t < 2; ++t) {
        const int cc = 4 * (j + 8 * t);
        const float4 ov = *(const float4*)&op[cc];
        const float o0 = ov.x, o1 = ov.y, o2 = ov.z, o3 = ov.w;   // raw target
        const float s0 = skf[4*t], s1 = skf[4*t+1], s2 = skf[4*t+2], s3 = skf[4*t+3];
        ss  += s0 + s1 + s2 + s3;
        sso += s0 * o0 + s1 * o1 + s2 * o2 + s3 * o3;
        const float4 xv = *(const float4*)&pp[cc];
        const float xs[4] = {xv.x, xv.y, xv.z, xv.w};
        const float ys[4] = {o0, o1, o2, o3};
        #pragma unroll
        for (int q = 0; q < 4; ++q) {
            const float x = xs[q], y = ys[q];
            const float zz = __expf(-fabsf(x));
            const float inv = 1.0f / (1.0f + zz);
            sb += fmaxf(x, 0.f) + __logf(1.0f + zz) - y * x;
            const float p = (x >= 0.f) ? inv : zz * inv;
            sp += p; sy += y; spy += p * y;
        }
    }
    for (int off = 32; off > 0; off >>= 1) {
        ss  += __shfl_down(ss,  off);
        sso += __shfl_down(sso, off);
        sb  += __shfl_down(sb,  off);
        sp  += __shfl_down(sp,  off);
        sy  += __shfl_down(sy,  off);
        spy += __shfl_down(spy, off);
    }
    const int wid = tid >> 6, lane = tid & 63;
    if (lane == 0) {
        red[0 * 8 + wid] = ss;  red[1 * 8 + wid] = sso;
        red[2 * 8 + wid] = sb;  red[3 * 8 + wid] = sp;
        red[4 * 8 + wid] = sy;  red[5 * 8 + wid] = spy;
    }
    __syncthreads();
    if (tid == 0) {
        double SS = 0, SO = 0, B0 = 0, B1 = 0, B2 = 0, B3 = 0;
        for (int w = 0; w < 8; ++w) {
            SS += (double)red[0 * 8 + w];  SO += (double)red[1 * 8 + w];
            B0 += (double)red[2 * 8 + w];  B1 += (double)red[3 * 8 + w];
            B2 += (double)red[4 * 8 + w];  B3 += (double)red[5 * 8 + w];
        }
        const int slot = bid & (SLOTS - 1);
        atomicAdd(&acc[slot * 8 + 4], SS);
        atomicAdd(&acc[slot * 8 + 5], SO);
        atomicAdd(&acc[slot * 8 + 0], B0);
        atomicAdd(&acc[slot * 8 + 1], B1);
        atomicAdd(&acc[slot * 8 + 2], B2);
        atomicAdd(&acc[slot * 8 + 3], B3);
    }
}

// ---------------------------------------------------------------------------
// Bool path: EXACT bit-packed skeleton of the binary target (verified r8).
// ---------------------------------------------------------------------------
__device__ __forceinline__
void bool_core(const float* __restrict__ tgt, const float* __restrict__ pred,
               double* __restrict__ acc, unsigned* bb, float* red,
               int z, int r0, int c0, int tid, int bid)
{
    unsigned* A  = bb;              // [RG*4]
    unsigned* B  = bb + RG * 4;
    unsigned* SK = bb + RG * 8;
    const float* tz = tgt + (size_t)z * NPIX;

    // ---- load + pack bits via wave ballot (row-major, 64+24 cols) ----
    {
        const int wv = tid >> 6, ln = tid & 63;
        for (int r = wv; r < RG; r += 8) {
            const int gr = min(max(r0 - HALO + r, 0), H_IMG - 1);
            const float* row = tz + (size_t)gr * W_IMG;
            const int gc = c0 - HALO + ln;
            const float v = row[min(max(gc, 0), W_IMG - 1)];
            const unsigned long long b0 = __ballot(v > 0.5f);
            float v2 = 0.f;
            if (ln < 24) v2 = row[min(max(gc + 64, 0), W_IMG - 1)];
            const unsigned long long b1 = __ballot((ln < 24) && (v2 > 0.5f));
            if (ln < 4) {
                const unsigned val = (ln == 0) ? (unsigned)b0
                                   : (ln == 1) ? (unsigned)(b0 >> 32)
                                   : (ln == 2) ? (unsigned)b1 : 0u;
                A[r * 4 + ln] = val;
            }
        }
    }
    __syncthreads();

    const int r = tid >> 2, w = tid & 3;
    const bool act = (tid < RG * 4);

    // out-of-image masks (1 = outside image)
    const int gcb = c0 - HALO + 32 * w;
    unsigned cm = 0;
    {
        const int lo = -gcb;
        if (lo > 0) cm |= (lo >= 32) ? 0xFFFFFFFFu : ((1u << lo) - 1u);
        const int hs = W_IMG - gcb;
        if (hs < 32) cm |= (hs <= 0) ? 0xFFFFFFFFu : ~((1u << hs) - 1u);
    }
    const int grs = r0 - HALO + r;
    const unsigned Mself = cm | ((((unsigned)grs)       >= (unsigned)H_IMG) ? 0xFFFFFFFFu : 0u);
    const unsigned Mup   = cm | ((((unsigned)(grs - 1)) >= (unsigned)H_IMG) ? 0xFFFFFFFFu : 0u);
    const unsigned Mdn   = cm | ((((unsigned)(grs + 1)) >= (unsigned)H_IMG) ? 0xFFFFFFFFu : 0u);
    const unsigned KILL  = ~Mself;

    const int iu = max(r - 1, 0) * 4 + w;
    const int id = min(r + 1, RG - 1) * 4 + w;

    unsigned mid  = act ? A[r * 4 + w] : 0u;
    unsigned skel = 0u;
    unsigned* sB = A; unsigned* dB = B;

    for (int k = 0; k < 11; ++k) {
        const unsigned me = mid | Mself;
        unsigned up = 0xFFFFFFFFu, dn = 0xFFFFFFFFu;
        if (act) { up = sB[iu] | Mup; dn = sB[id] | Mdn; }
        const unsigned pv = (unsigned)__shfl_up((int)me, 1);
        const unsigned nx = (unsigned)__shfl_down((int)me, 1);
        const unsigned Lh = (me << 1) | (pv >> 31);
        const unsigned Rh = (me >> 1) | (nx << 31);
        const unsigned e  = (me & up & dn & Lh & Rh) & KILL;
        if (act) dB[r * 4 + w] = e;
        __syncthreads();
        unsigned eu = 0, ed = 0;
        if (act) { eu = dB[iu]; ed = dB[id]; }
        const unsigned V  = e | eu | ed;
        const unsigned pV = (unsigned)__shfl_up((int)V, 1);
        const unsigned nV = (unsigned)__shfl_down((int)V, 1);
        const unsigned open = V | ((V << 1) | (pV >> 31)) | ((V >> 1) | (nV << 31));
        skel |= mid & ~open;
        mid = e;
        unsigned* tp = sB; sB = dB; dB = tp;
    }
    if (act) SK[r * 4 + w] = skel;
    __syncthreads();

    // ---- epilogue: ss = sum(skel bits), sso = sum(skel * sigmoid(pred)) ----
    const int oy = tid >> 3, j = tid & 7;
    const size_t gbase = (size_t)z * NPIX + (size_t)(r0 + oy) * W_IMG + c0;
    const float* pp = pred + gbase;
    float ss = 0.f, sso = 0.f;
    #pragma unroll
    for (int t = 0; t < 2; ++t) {
        const int cc  = 4 * (j + 8 * t);
        const int rcb = HALO + cc;
        const unsigned wd = SK[(HALO + oy) * 4 + (rcb >> 5)] >> (rcb & 31);
        const float4 xv = *(const float4*)&pp[cc];
        const float p0 = sigm(xv.x), p1 = sigm(xv.y), p2 = sigm(xv.z), p3 = sigm(xv.w);
        const float b0 = (float)( wd       & 1u);
        const float b1 = (float)((wd >> 1) & 1u);
        const float b2 = (float)((wd >> 2) & 1u);
        const float b3 = (float)((wd >> 3) & 1u);
        ss  += b0 + b1 + b2 + b3;
        sso += b0 * p0 + b1 * p1 + b2 * p2 + b3 * p3;
    }
    for (int off = 32; off > 0; off >>= 1) {
        ss  += __shfl_down(ss,  off);
        sso += __shfl_down(sso, off);
    }
    const int wid = tid >> 6, lane = tid & 63;
    if (lane == 0) { red[0 * 8 + wid] = ss; red[1 * 8 + wid] = sso; }
    __syncthreads();
    if (tid == 0) {
        double SS = 0, SO = 0;
        for (int wq = 0; wq < 8; ++wq) { SS += (double)red[0 * 8 + wq]; SO += (double)red[1 * 8 + wq]; }
        const int slot = bid & (SLOTS - 1);
        atomicAdd(&acc[slot * 8 + 6], SS);
        atomicAdd(&acc[slot * 8 + 7], SO);
    }
}

// One dispatch. Type alternates per GROUP OF 8 consecutive fids (not per fid:
// consecutive ids round-robin across the 8 XCDs, so per-fid parity pins each
// type to half the XCDs -- r10 regression). Within a group, 8 tiles; both
// types sweep all tiles/XCDs uniformly and stay co-resident over time.
__global__ __launch_bounds__(512, 8)
void skel_all(const float* __restrict__ pred, const float* __restrict__ tgt,
              double* __restrict__ acc)
{
    __shared__ __align__(16) __half buf0[RG * HST];
    __shared__ __align__(16) __half buf1[RG * HST];
    __shared__ float red[48];
    const int tid = threadIdx.x;
    const int fid = ((int)blockIdx.z * (int)gridDim.y + (int)blockIdx.y) * (int)gridDim.x
                    + (int)blockIdx.x;            // 0..8191, x fastest
    const int typ  = (fid >> 3) & 1;              // alternate every 8 blocks
    const int tile = (fid & 7) | ((fid >> 4) << 3);   // 0..4095
    const int x = tile & 15, y = (tile >> 4) & 15, z = tile >> 8;
    const int r0 = y * TILE, c0 = x * TILE;
    if (typ == 0)
        skel_f16(pred, tgt, acc, buf0, buf1, red, z, r0, c0, tid, tile);
    else
        bool_core(tgt, pred, acc, (unsigned*)buf0, red, z, r0, c0, tid, tile);
}

__global__ void zero_acc(double* acc) { acc[threadIdx.x] = 0.0; }

__global__ void finalize_k(const double* __restrict__ acc, float* __restrict__ out)
{
    __shared__ double S[8];
    const int jj = threadIdx.x;
    if (jj < 8) {
        double t = 0.0;
        for (int s = 0; s < SLOTS; ++s) t += acc[s * 8 + jj];
        S[jj] = t;
    }
    __syncthreads();
    if (jj == 0) {
        const double bce   = S[0] / (double)N_TOT;
        const double dice  = (2.0 * S[3] + 1.0) / (S[1] + S[2] + 1.0);
        const double tprec = (S[5] + 1.0) / (S[4] + 1.0);
        const double tsens = (S[7] + 1.0) / (S[6] + 1.0);
        const double cl    = 2.0 * tprec * tsens / (tprec + tsens + 1e-7);
        out[0] = (float)(0.3 * bce + 0.3 * (1.0 - dice) + 0.4 * (1.0 - cl));
    }
}

// ---------------------------------------------------------------------------
extern "C" void kernel_launch(void* const* d_in, const int* in_sizes, int n_in,
                              void* d_out, int out_size, void* d_ws, size_t ws_size,
                              hipStream_t stream)
{
    const float* pred = (const float*)d_in[0];
    const float* tgt  = (const float*)d_in[1];
    float* out = (float*)d_out;
    double* acc = (double*)d_ws;                  // SLOTS*8 doubles = 2 KB

    zero_acc<<<1, SLOTS * 8, 0, stream>>>(acc);

    const dim3 grid(16, 16, 32);                  // 8192 blocks, group-of-8 interleave
    skel_all<<<grid, 512, 0, stream>>>(pred, tgt, acc);

    finalize_k<<<1, 64, 0, stream>>>(acc, out);
}

// Round 12
// 264.483 us; speedup vs baseline: 1.5601x; 1.5371x over previous
//
#include <hip/hip_runtime.h>
#include <hip/hip_fp16.h>
#include <math.h>

// Geometry (fixed): B=16, C=1, H=W=1024, f32.
#define H_IMG 1024
#define W_IMG 1024
#define N_B   16
#define NPIX  (H_IMG * W_IMG)
#define N_TOT (16LL * NPIX)

// 64x64 owned tile, halo 12 (11 fused erode iters + 1 dilate ring).
// z<16: f16 skeleton of sigmoid(pred) (fp16 LDS + packed-f16), r8's verified
// 2-barrier schedule + register-carried er_k[owned]. z>=16: exact bit-packed
// Boolean skeleton of the binary target (verified r8).
// NOTE (r10/r11 lesson): do NOT interleave the two block types in one
// dispatch -- both XCD-pinned and per-CU-mixed layouts measured ~1.55x slower.
// The natural z-ordered dispatch (f16 phase then bool phase) is the fast one.
#define TILE 64
#define HALO 12
#define RG   88          // TILE + 2*HALO rows / data cols
#define HST  92          // f16 LDS row stride in halfs (184 B)
#define SLOTS 32         // atomic accumulator slots (each its own 64B line)

#define PK_NINF 0xFC00FC00u   // {-inf,-inf} f16x2
#define PK_SGN  0x80008000u   // packed sign-flip mask

__device__ __forceinline__ float sigm(float x)  { return 1.0f / (1.0f + __expf(-x)); }

// ---- packed f16 reg ops (pure VALU, no memory: asm ordering is safe) ----
__device__ __forceinline__ unsigned pk_min(unsigned a, unsigned b) {
    unsigned r; asm("v_pk_min_f16 %0, %1, %2" : "=v"(r) : "v"(a), "v"(b)); return r;
}
__device__ __forceinline__ unsigned pk_max(unsigned a, unsigned b) {
    unsigned r; asm("v_pk_max_f16 %0, %1, %2" : "=v"(r) : "v"(a), "v"(b)); return r;
}
__device__ __forceinline__ unsigned pk_add(unsigned a, unsigned b) {
    unsigned r; asm("v_pk_add_f16 %0, %1, %2" : "=v"(r) : "v"(a), "v"(b)); return r;
}
__device__ __forceinline__ unsigned pk_fma(unsigned a, unsigned b, unsigned c) {
    unsigned r; asm("v_pk_fma_f16 %0, %1, %2, %3" : "=v"(r) : "v"(a), "v"(b), "v"(c)); return r;
}
// {hi.low16, lo.high16}: result low half = lo's HIGH half, high half = hi's LOW half.
__device__ __forceinline__ unsigned alignb(unsigned hi, unsigned lo) {
    unsigned r; asm("v_alignbit_b32 %0, %1, %2, 16" : "=v"(r) : "v"(hi), "v"(lo)); return r;
}

union H2U { __half2 h; unsigned u; };

__device__ __forceinline__ uint2 ld2u(const __half* p) { return *(const uint2*)p; }
__device__ __forceinline__ void  st2u(__half* p, unsigned a, unsigned b) { *(uint2*)p = make_uint2(a, b); }
__device__ __forceinline__ void st4h(__half* p, float x, float y, float z, float w) {
    H2U a, b;
    a.h = __floats2half2_rn(x, y);
    b.h = __floats2half2_rn(z, w);
    *(uint2*)p = make_uint2(a.u, b.u);
}

// Overwrite region cells whose GLOBAL coords are outside the image with +INF
// (erode-input identity). b16 stores, consecutive addresses: conflict-free.
__device__ __forceinline__ void band_fix_inf(__half* b, int r0, int c0, int tid)
{
    unsigned short* u = (unsigned short*)b;
    const unsigned short val = 0x7C00;   // +inf f16
    if (r0 == 0) {
        for (int idx = tid; idx < HALO * RG; idx += 512) {
            const int r = idx / RG, c = idx - r * RG;
            u[r * HST + c] = val;
        }
    }
    if (r0 == H_IMG - TILE) {
        for (int idx = tid; idx < HALO * RG; idx += 512) {
            const int r = idx / RG, c = idx - r * RG;
            u[(RG - HALO + r) * HST + c] = val;
        }
    }
    if (c0 == 0) {
        for (int idx = tid; idx < RG * HALO; idx += 512) {
            const int r = idx / HALO, c = idx - r * HALO;
            u[r * HST + c] = val;
        }
    }
    if (c0 == W_IMG - TILE) {
        for (int idx = tid; idx < RG * HALO; idx += 512) {
            const int r = idx / HALO, c = idx - r * HALO;
            u[r * HST + (RG - HALO + c)] = val;
        }
    }
}

// ---------------------------------------------------------------------------
// One erode pass er_k(cur) -> er_{k+1}(nxt), rows [k+1, 87-k), trimmed strips.
// Bank design: b64 strip ops = 1 row x {16,8} consecutive strips per lane
// group (2-way, free); horizontal neighbors via __shfl + v_alignbit; strip-
// boundary lanes fall back to scalar u16 LDS reads (distinct rows -> banks).
// ---------------------------------------------------------------------------
template<bool EDGE>
__device__ __forceinline__
void erode_step(const __half* cur, __half* nxt, int k, int r0, int c0, int tid)
{
    const int rlo = k + 1, rhi = RG - 1 - k;        // rows [rlo, rhi)
    const int sA = rlo >> 2, sE = (rhi + 3) >> 2;   // strips [sA, sE)

    // ---- phase A: strips sA..sA+15 (1 row x 16 strips/quarter) ----
    {
        const int l  = tid & 15;
        const int st = sA + l;
        const int c  = 4 * st;
        bool cOOB = false;
        if (EDGE) {
            const int gcb = c0 - HALO + c;
            cOOB = ((unsigned)gcb > (unsigned)(W_IMG - 4));
        }
        for (int r = rlo + (tid >> 4); r < rhi; r += 32) {
            const int base = r * HST + c;
            const uint2 mid = ld2u(&cur[base]);
            const uint2 up  = ld2u(&cur[base - HST]);
            const uint2 dn  = ld2u(&cur[base + HST]);
            unsigned lfreg = (unsigned)__shfl_up((int)mid.y, 1);    // left strip m23
            unsigned rtreg = (unsigned)__shfl_down((int)mid.x, 1);  // right strip m01
            if (l == 0)  lfreg = ((unsigned)*(const unsigned short*)(cur + base - 1)) << 16;
            if (l == 15) rtreg = (unsigned)*(const unsigned short*)(cur + base + 4);
            const unsigned L01 = alignb(mid.x, lfreg);   // [m-1, m0]
            const unsigned L23 = alignb(mid.y, mid.x);   // [m1 , m2] (== R01)
            const unsigned R23 = alignb(rtreg, mid.y);   // [m3 , m4]
            unsigned e01 = pk_min(pk_min(pk_min(up.x, dn.x), mid.x), pk_min(L01, L23));
            unsigned e23 = pk_min(pk_min(pk_min(up.y, dn.y), mid.y), pk_min(L23, R23));
            if (EDGE) {
                const int gr = r0 - HALO + r;
                if (((unsigned)gr >= (unsigned)H_IMG) | cOOB) { e01 = PK_NINF; e23 = PK_NINF; }
            }
            st2u(&nxt[base], e01, e23);
        }
    }
    // ---- phase B: strips sA+16..sE-1 (2 rows x 8 strips/quarter) ----
    {
        const int l  = tid & 7;
        const int st = sA + 16 + l;
        if (st < sE) {
            const int c = 4 * st;
            bool cOOB = false;
            if (EDGE) {
                const int gcb = c0 - HALO + c;
                cOOB = ((unsigned)gcb > (unsigned)(W_IMG - 4));
            }
            const bool lastS = (st == sE - 1);
            for (int r = rlo + (tid >> 3); r < rhi; r += 64) {
                const int base = r * HST + c;
                const uint2 mid = ld2u(&cur[base]);
                const uint2 up  = ld2u(&cur[base - HST]);
                const uint2 dn  = ld2u(&cur[base + HST]);
                unsigned lfreg = (unsigned)__shfl_up((int)mid.y, 1);
                unsigned rtreg = (unsigned)__shfl_down((int)mid.x, 1);
                if (l == 0)  lfreg = ((unsigned)*(const unsigned short*)(cur + base - 1)) << 16;
                if (lastS)   rtreg = (unsigned)*(const unsigned short*)(cur + base + 4);
                const unsigned L01 = alignb(mid.x, lfreg);
                const unsigned L23 = alignb(mid.y, mid.x);
                const unsigned R23 = alignb(rtreg, mid.y);
                unsigned e01 = pk_min(pk_min(pk_min(up.x, dn.x), mid.x), pk_min(L01, L23));
                unsigned e23 = pk_min(pk_min(pk_min(up.y, dn.y), mid.y), pk_min(L23, R23));
                if (EDGE) {
                    const int gr = r0 - HALO + r;
                    if (((unsigned)gr >= (unsigned)H_IMG) | cOOB) { e01 = PK_NINF; e23 = PK_NINF; }
                }
                st2u(&nxt[base], e01, e23);
            }
        }
    }
}

// ---------------------------------------------------------------------------
// Dilate-open of `buf` at this thread's owned strips (separable V/H, packed).
// Returns open values and the owned mid rows (m0,m1) for register carry.
// ---------------------------------------------------------------------------
struct OpenV { unsigned oA01, oA23, oB01, oB23; uint2 m0, m1; };

__device__ __forceinline__
OpenV dilate_open(const __half* buf, int bA, int bB, int j)
{
    OpenV R;
    const uint2 a0 = ld2u(&buf[bA - HST]);
    R.m0           = ld2u(&buf[bA]);
    const uint2 d0 = ld2u(&buf[bA + HST]);
    const uint2 a1 = ld2u(&buf[bB - HST]);
    R.m1           = ld2u(&buf[bB]);
    const uint2 d1 = ld2u(&buf[bB + HST]);
    const unsigned VA01 = pk_max(pk_max(a0.x, R.m0.x), d0.x);
    const unsigned VA23 = pk_max(pk_max(a0.y, R.m0.y), d0.y);
    const unsigned VB01 = pk_max(pk_max(a1.x, R.m1.x), d1.x);
    const unsigned VB23 = pk_max(pk_max(a1.y, R.m1.y), d1.y);
    // horizontal neighbor regs (hi/lo halves used via alignb)
    unsigned vlA = (unsigned)__shfl_up((int)VA23, 1);        // high = V[cA-1]
    const unsigned vrAa = (unsigned)__shfl_down((int)VA01, 1);
    const unsigned vrAb = (unsigned)__shfl_up((int)VB01, 7); // j==7 seam: strip 8
    unsigned vrA = (j == 7) ? vrAb : vrAa;                   // low = V[cA+4]
    const unsigned vlBa = (unsigned)__shfl_up((int)VB23, 1);
    const unsigned vlBb = (unsigned)__shfl_down((int)VA23, 7); // j==0 seam: strip 7
    unsigned vlB = (j == 0) ? vlBb : vlBa;                   // high = V[cB-1]
    unsigned vrB = (unsigned)__shfl_down((int)VB01, 1);      // low = V[cB+4]
    if (j == 0) {   // block-left halo col: scalar u16 vertical max
        const unsigned t1 = *(const unsigned short*)(buf + bA - HST - 1);
        const unsigned t2 = *(const unsigned short*)(buf + bA - 1);
        const unsigned t3 = *(const unsigned short*)(buf + bA + HST - 1);
        vlA = pk_max(pk_max(t1, t2), t3) << 16;              // value -> high half
    }
    if (j == 7) {   // block-right halo col
        const unsigned t1 = *(const unsigned short*)(buf + bB - HST + 4);
        const unsigned t2 = *(const unsigned short*)(buf + bB + 4);
        const unsigned t3 = *(const unsigned short*)(buf + bB + HST + 4);
        vrB = pk_max(pk_max(t1, t2), t3);                    // value in low half
    }
    const unsigned LA = alignb(VA01, vlA);    // [V-1, V0]
    const unsigned MA = alignb(VA23, VA01);   // [V1 , V2]
    const unsigned RA = alignb(vrA,  VA23);   // [V3 , V4]
    R.oA01 = pk_max(pk_max(LA, MA), VA01);
    R.oA23 = pk_max(pk_max(MA, RA), VA23);
    const unsigned LB = alignb(VB01, vlB);
    const unsigned MB = alignb(VB23, VB01);
    const unsigned RB = alignb(vrB,  VB23);
    R.oB01 = pk_max(pk_max(LB, MB), VB01);
    R.oB23 = pk_max(pk_max(MB, RB), VB23);
    return R;
}

// delta = relu(e - open); skel += relu(delta - skel*delta)   (packed f16)
__device__ __forceinline__ void skel_upd(unsigned& sk, unsigned e, unsigned o)
{
    const unsigned d = pk_max(pk_add(e, o ^ PK_SGN), 0u);
    const unsigned u = pk_max(pk_fma(sk ^ PK_SGN, d, d), 0u);
    sk = pk_add(sk, u);
}

// ---------------------------------------------------------------------------
// f16 path: whole soft_skeleton of sigmoid(pred), fused BCE/dice + skel
// reductions. r8's 2-barrier schedule; er_k[owned] carried in registers.
// ---------------------------------------------------------------------------
__device__ __forceinline__
void skel_f16(const float* __restrict__ pred, const float* __restrict__ tgt,
              double* __restrict__ acc, __half* cur, __half* nxt, float* red,
              int z, int r0, int c0, int tid, int bid)
{
    const float* s = pred + (size_t)z * NPIX;

    // ---- load 88x88 region (+4-col pad), phase-aligned, sigmoid applied ----
    {   // phase A: strips 0..15, 1 row x 16 strips per quarter-wave
        const int st = tid & 15, c = 4 * st;
        const int gc = c0 - HALO + c;
        const bool vec = (gc >= 0) && (gc + 3 < W_IMG);
        for (int r = tid >> 4; r < RG; r += 32) {
            const int gr = min(max(r0 - HALO + r, 0), H_IMG - 1);
            const float* row = s + (size_t)gr * W_IMG;
            float4 v;
            if (vec) v = *(const float4*)&row[gc];
            else {
                v.x = row[min(max(gc + 0, 0), W_IMG - 1)];
                v.y = row[min(max(gc + 1, 0), W_IMG - 1)];
                v.z = row[min(max(gc + 2, 0), W_IMG - 1)];
                v.w = row[min(max(gc + 3, 0), W_IMG - 1)];
            }
            st4h(&cur[r * HST + c], sigm(v.x), sigm(v.y), sigm(v.z), sigm(v.w));
        }
    }
    {   // phase B: strips 16..22 (incl pad strip 22), 2 rows x 8 strips
        const int st = 16 + (tid & 7);
        if (st < 23) {
            const int c = 4 * st, gc = c0 - HALO + c;
            const bool vec = (gc >= 0) && (gc + 3 < W_IMG);
            for (int r = tid >> 3; r < RG; r += 64) {
                const int gr = min(max(r0 - HALO + r, 0), H_IMG - 1);
                const float* row = s + (size_t)gr * W_IMG;
                float4 v;
                if (vec) v = *(const float4*)&row[gc];
                else {
                    v.x = row[min(max(gc + 0, 0), W_IMG - 1)];
                    v.y = row[min(max(gc + 1, 0), W_IMG - 1)];
                    v.z = row[min(max(gc + 2, 0), W_IMG - 1)];
                    v.w = row[min(max(gc + 3, 0), W_IMG - 1)];
                }
                st4h(&cur[r * HST + c], sigm(v.x), sigm(v.y), sigm(v.z), sigm(v.w));
            }
        }
    }
    __syncthreads();

    const bool edge = (r0 == 0) | (c0 == 0) | (r0 == H_IMG - TILE) | (c0 == W_IMG - TILE);

    unsigned skA01 = 0, skA23 = 0, skB01 = 0, skB23 = 0;

    const int oy = tid >> 3;      // owned row 0..63
    const int j  = tid & 7;       // strip slot (strips j, j+8 of owned)
    const int rr = HALO + oy;
    const int bA = rr * HST + HALO + 4 * j;
    const int bB = bA + 32;

    // er_0[owned] -> registers (band_fix never touches owned cells)
    uint2 eA = ld2u(&cur[bA]);
    uint2 eB = ld2u(&cur[bB]);

    if (!edge) {
        // ===== interior: r8's 2-barrier schedule + register carry =====
        #pragma unroll 1
        for (int k = 0; k <= 10; ++k) {
            erode_step<false>(cur, nxt, k, r0, c0, tid);
            __syncthreads();
            const OpenV R = dilate_open(nxt, bA, bB, j);   // open_k = dilate(er_{k+1})
            skel_upd(skA01, eA.x, R.oA01);
            skel_upd(skA23, eA.y, R.oA23);
            skel_upd(skB01, eB.x, R.oB01);
            skel_upd(skB23, eB.y, R.oB23);
            eA = R.m0; eB = R.m1;                          // er_{k+1}[owned], free
            __syncthreads();
            __half* tp = cur; cur = nxt; nxt = tp;
        }
    } else {
        // ===== edge blocks: verified 3-barrier path + register carry =====
        #pragma unroll 1
        for (int k = 0; k <= 10; ++k) {
            band_fix_inf(cur, r0, c0, tid);
            __syncthreads();
            erode_step<true>(cur, nxt, k, r0, c0, tid);
            __syncthreads();
            const OpenV R = dilate_open(nxt, bA, bB, j);   // dilate(er_{k+1})
            skel_upd(skA01, eA.x, R.oA01);
            skel_upd(skA23, eA.y, R.oA23);
            skel_upd(skB01, eB.x, R.oB01);
            skel_upd(skB23, eB.y, R.oB23);
            eA = R.m0; eB = R.m1;
            __syncthreads();
            __half* tp = cur; cur = nxt; nxt = tp;
        }
    }

    // ---- unpack skel to f32 ----
    float skf[8];
    {
        H2U u; float2 f;
        u.u = skA01; f = __half22float2(u.h); skf[0] = f.x; skf[1] = f.y;
        u.u = skA23; f = __half22float2(u.h); skf[2] = f.x; skf[3] = f.y;
        u.u = skB01; f = __half22float2(u.h); skf[4] = f.x; skf[5] = f.y;
        u.u = skB23; f = __half22float2(u.h); skf[6] = f.x; skf[7] = f.y;
    }

    // ---- fused reductions over owned pixels: skel sums + BCE/dice ----
    const size_t gbase = (size_t)z * NPIX + (size_t)(r0 + oy) * W_IMG + c0;
    const float* op = tgt  + gbase;
    const float* pp = pred + gbase;
    float ss = 0.f, sso = 0.f, sb = 0.f, sp = 0.f, sy = 0.f, spy = 0.f;
    #pragma unroll
    for (int t = 0; t < 2; ++t) {
        const int cc = 4 * (j + 8 * t);
        const float4 ov = *(const float4*)&op[cc];
        const float o0 = ov.x, o1 = ov.y, o2 = ov.z, o3 = ov.w;   // raw target
        const float s0 = skf[4*t], s1 = skf[4*t+1], s2 = skf[4*t+2], s3 = skf[4*t+3];
        ss  += s0 + s1 + s2 + s3;
        sso += s0 * o0 + s1 * o1 + s2 * o2 + s3 * o3;
        const float4 xv = *(const float4*)&pp[cc];
        const float xs[4] = {xv.x, xv.y, xv.z, xv.w};
        const float ys[4] = {o0, o1, o2, o3};
        #pragma unroll
        for (int q = 0; q < 4; ++q) {
            const float x = xs[q], y = ys[q];
            const float zz = __expf(-fabsf(x));
            const float inv = 1.0f / (1.0f + zz);
            sb += fmaxf(x, 0.f) + __logf(1.0f + zz) - y * x;
            const float p = (x >= 0.f) ? inv : zz * inv;
            sp += p; sy += y; spy += p * y;
        }
    }
    for (int off = 32; off > 0; off >>= 1) {
        ss  += __shfl_down(ss,  off);
        sso += __shfl_down(sso, off);
        sb  += __shfl_down(sb,  off);
        sp  += __shfl_down(sp,  off);
        sy  += __shfl_down(sy,  off);
        spy += __shfl_down(spy, off);
    }
    const int wid = tid >> 6, lane = tid & 63;
    if (lane == 0) {
        red[0 * 8 + wid] = ss;  red[1 * 8 + wid] = sso;
        red[2 * 8 + wid] = sb;  red[3 * 8 + wid] = sp;
        red[4 * 8 + wid] = sy;  red[5 * 8 + wid] = spy;
    }
    __syncthreads();
    if (tid == 0) {
        double SS = 0, SO = 0, B0 = 0, B1 = 0, B2 = 0, B3 = 0;
        for (int w = 0; w < 8; ++w) {
            SS += (double)red[0 * 8 + w];  SO += (double)red[1 * 8 + w];
            B0 += (double)red[2 * 8 + w];  B1 += (double)red[3 * 8 + w];
            B2 += (double)red[4 * 8 + w];  B3 += (double)red[5 * 8 + w];
        }
        const int slot = bid & (SLOTS - 1);
        atomicAdd(&acc[slot * 8 + 4], SS);
        atomicAdd(&acc[slot * 8 + 5], SO);
        atomicAdd(&acc[slot * 8 + 0], B0);
        atomicAdd(&acc[slot * 8 + 1], B1);
        atomicAdd(&acc[slot * 8 + 2], B2);
        atomicAdd(&acc[slot * 8 + 3], B3);
    }
}

// ---------------------------------------------------------------------------
// Bool path: EXACT bit-packed skeleton of the binary target (verified r8).
// ---------------------------------------------------------------------------
__device__ __forceinline__
void bool_core(const float* __restrict__ tgt, const float* __restrict__ pred,
               double* __restrict__ acc, unsigned* bb, float* red,
               int z, int r0, int c0, int tid, int bid)
{
    unsigned* A  = bb;              // [RG*4]
    unsigned* B  = bb + RG * 4;
    unsigned* SK = bb + RG * 8;
    const float* tz = tgt + (size_t)z * NPIX;

    // ---- load + pack bits via wave ballot (row-major, 64+24 cols) ----
    {
        const int wv = tid >> 6, ln = tid & 63;
        for (int r = wv; r < RG; r += 8) {
            const int gr = min(max(r0 - HALO + r, 0), H_IMG - 1);
            const float* row = tz + (size_t)gr * W_IMG;
            const int gc = c0 - HALO + ln;
            const float v = row[min(max(gc, 0), W_IMG - 1)];
            const unsigned long long b0 = __ballot(v > 0.5f);
            float v2 = 0.f;
            if (ln < 24) v2 = row[min(max(gc + 64, 0), W_IMG - 1)];
            const unsigned long long b1 = __ballot((ln < 24) && (v2 > 0.5f));
            if (ln < 4) {
                const unsigned val = (ln == 0) ? (unsigned)b0
                                   : (ln == 1) ? (unsigned)(b0 >> 32)
                                   : (ln == 2) ? (unsigned)b1 : 0u;
                A[r * 4 + ln] = val;
            }
        }
    }
    __syncthreads();

    const int r = tid >> 2, w = tid & 3;
    const bool act = (tid < RG * 4);

    // out-of-image masks (1 = outside image)
    const int gcb = c0 - HALO + 32 * w;
    unsigned cm = 0;
    {
        const int lo = -gcb;
        if (lo > 0) cm |= (lo >= 32) ? 0xFFFFFFFFu : ((1u << lo) - 1u);
        const int hs = W_IMG - gcb;
        if (hs < 32) cm |= (hs <= 0) ? 0xFFFFFFFFu : ~((1u << hs) - 1u);
    }
    const int grs = r0 - HALO + r;
    const unsigned Mself = cm | ((((unsigned)grs)       >= (unsigned)H_IMG) ? 0xFFFFFFFFu : 0u);
    const unsigned Mup   = cm | ((((unsigned)(grs - 1)) >= (unsigned)H_IMG) ? 0xFFFFFFFFu : 0u);
    const unsigned Mdn   = cm | ((((unsigned)(grs + 1)) >= (unsigned)H_IMG) ? 0xFFFFFFFFu : 0u);
    const unsigned KILL  = ~Mself;

    const int iu = max(r - 1, 0) * 4 + w;
    const int id = min(r + 1, RG - 1) * 4 + w;

    unsigned mid  = act ? A[r * 4 + w] : 0u;
    unsigned skel = 0u;
    unsigned* sB = A; unsigned* dB = B;

    for (int k = 0; k < 11; ++k) {
        const unsigned me = mid | Mself;
        unsigned up = 0xFFFFFFFFu, dn = 0xFFFFFFFFu;
        if (act) { up = sB[iu] | Mup; dn = sB[id] | Mdn; }
        const unsigned pv = (unsigned)__shfl_up((int)me, 1);
        const unsigned nx = (unsigned)__shfl_down((int)me, 1);
        const unsigned Lh = (me << 1) | (pv >> 31);
        const unsigned Rh = (me >> 1) | (nx << 31);
        const unsigned e  = (me & up & dn & Lh & Rh) & KILL;
        if (act) dB[r * 4 + w] = e;
        __syncthreads();
        unsigned eu = 0, ed = 0;
        if (act) { eu = dB[iu]; ed = dB[id]; }
        const unsigned V  = e | eu | ed;
        const unsigned pV = (unsigned)__shfl_up((int)V, 1);
        const unsigned nV = (unsigned)__shfl_down((int)V, 1);
        const unsigned open = V | ((V << 1) | (pV >> 31)) | ((V >> 1) | (nV << 31));
        skel |= mid & ~open;
        mid = e;
        unsigned* tp = sB; sB = dB; dB = tp;
    }
    if (act) SK[r * 4 + w] = skel;
    __syncthreads();

    // ---- epilogue: ss = sum(skel bits), sso = sum(skel * sigmoid(pred)) ----
    const int oy = tid >> 3, j = tid & 7;
    const size_t gbase = (size_t)z * NPIX + (size_t)(r0 + oy) * W_IMG + c0;
    const float* pp = pred + gbase;
    float ss = 0.f, sso = 0.f;
    #pragma unroll
    for (int t = 0; t < 2; ++t) {
        const int cc  = 4 * (j + 8 * t);
        const int rcb = HALO + cc;
        const unsigned wd = SK[(HALO + oy) * 4 + (rcb >> 5)] >> (rcb & 31);
        const float4 xv = *(const float4*)&pp[cc];
        const float p0 = sigm(xv.x), p1 = sigm(xv.y), p2 = sigm(xv.z), p3 = sigm(xv.w);
        const float b0 = (float)( wd       & 1u);
        const float b1 = (float)((wd >> 1) & 1u);
        const float b2 = (float)((wd >> 2) & 1u);
        const float b3 = (float)((wd >> 3) & 1u);
        ss  += b0 + b1 + b2 + b3;
        sso += b0 * p0 + b1 * p1 + b2 * p2 + b3 * p3;
    }
    for (int off = 32; off > 0; off >>= 1) {
        ss  += __shfl_down(ss,  off);
        sso += __shfl_down(sso, off);
    }
    const int wid = tid >> 6, lane = tid & 63;
    if (lane == 0) { red[0 * 8 + wid] = ss; red[1 * 8 + wid] = sso; }
    __syncthreads();
    if (tid == 0) {
        double SS = 0, SO = 0;
        for (int wq = 0; wq < 8; ++wq) { SS += (double)red[0 * 8 + wq]; SO += (double)red[1 * 8 + wq]; }
        const int slot = bid & (SLOTS - 1);
        atomicAdd(&acc[slot * 8 + 6], SS);
        atomicAdd(&acc[slot * 8 + 7], SO);
    }
}

// Both skeletons in one dispatch, r8's z-split (f16 phase sweeps the whole
// machine first, bool phase follows -- measured fastest layout).
__global__ __launch_bounds__(512, 8)
void skel_all(const float* __restrict__ pred, const float* __restrict__ tgt,
              double* __restrict__ acc)
{
    __shared__ __align__(16) __half buf0[RG * HST];
    __shared__ __align__(16) __half buf1[RG * HST];
    __shared__ float red[48];
    const int tid = threadIdx.x;
    const int r0 = blockIdx.y * TILE, c0 = blockIdx.x * TILE;
    const int bid = ((int)blockIdx.z & 15) * 256 + blockIdx.y * 16 + blockIdx.x;
    if ((int)blockIdx.z < N_B)
        skel_f16(pred, tgt, acc, buf0, buf1, red, blockIdx.z, r0, c0, tid, bid);
    else
        bool_core(tgt, pred, acc, (unsigned*)buf0, red,
                  (int)blockIdx.z - N_B, r0, c0, tid, bid);
}

__global__ void zero_acc(double* acc) { acc[threadIdx.x] = 0.0; }

__global__ void finalize_k(const double* __restrict__ acc, float* __restrict__ out)
{
    __shared__ double S[8];
    const int jj = threadIdx.x;
    if (jj < 8) {
        double t = 0.0;
        for (int s = 0; s < SLOTS; ++s) t += acc[s * 8 + jj];
        S[jj] = t;
    }
    __syncthreads();
    if (jj == 0) {
        const double bce   = S[0] / (double)N_TOT;
        const double dice  = (2.0 * S[3] + 1.0) / (S[1] + S[2] + 1.0);
        const double tprec = (S[5] + 1.0) / (S[4] + 1.0);
        const double tsens = (S[7] + 1.0) / (S[6] + 1.0);
        const double cl    = 2.0 * tprec * tsens / (tprec + tsens + 1e-7);
        out[0] = (float)(0.3 * bce + 0.3 * (1.0 - dice) + 0.4 * (1.0 - cl));
    }
}

// ---------------------------------------------------------------------------
extern "C" void kernel_launch(void* const* d_in, const int* in_sizes, int n_in,
                              void* d_out, int out_size, void* d_ws, size_t ws_size,
                              hipStream_t stream)
{
    const float* pred = (const float*)d_in[0];
    const float* tgt  = (const float*)d_in[1];
    float* out = (float*)d_out;
    double* acc = (double*)d_ws;                  // SLOTS*8 doubles = 2 KB

    zero_acc<<<1, SLOTS * 8, 0, stream>>>(acc);

    const dim3 grid(16, 16, 32);                  // z<16: f16, z>=16: bool
    skel_all<<<grid, 512, 0, stream>>>(pred, tgt, acc);

    finalize_k<<<1, 64, 0, stream>>>(acc, out);
}

// Round 13
// 260.097 us; speedup vs baseline: 1.5864x; 1.0169x over previous
//
#include <hip/hip_runtime.h>
#include <hip/hip_fp16.h>
#include <math.h>

// Geometry (fixed): B=16, C=1, H=W=1024, f32.
#define H_IMG 1024
#define W_IMG 1024
#define N_B   16
#define NPIX  (H_IMG * W_IMG)
#define N_TOT (16LL * NPIX)

// 64x64 owned tile, halo 12 (11 fused erode iters + 1 dilate ring).
// z<16 (sigmoid(pred) skeleton): fp16 LDS + packed-f16 math (r7/r8 verified).
// z>=16 (target skeleton): target is EXACTLY {0,1} -> Boolean morphology,
// bit-packed 32 px/u32 (erode=AND-plus, dilate=OR-3x3, skel|=er&~open). Exact.
// This is the r8 configuration verbatim -- best measured (258.7 us). Tested
// neighbors all worse: merged 1-barrier (-4%), er-register-carry (-2%),
// type-interleaved dispatch (-55%, XCD pinning / per-CU mixing pathology).
#define TILE 64
#define HALO 12
#define RG   88          // TILE + 2*HALO rows / data cols
#define HST  92          // f16 LDS row stride in halfs (184 B)
#define SLOTS 32         // atomic accumulator slots (each its own 64B line)

#define PK_NINF 0xFC00FC00u   // {-inf,-inf} f16x2
#define PK_SGN  0x80008000u   // packed sign-flip mask

__device__ __forceinline__ float sigm(float x)  { return 1.0f / (1.0f + __expf(-x)); }

// ---- packed f16 reg ops (pure VALU, no memory: asm ordering is safe) ----
__device__ __forceinline__ unsigned pk_min(unsigned a, unsigned b) {
    unsigned r; asm("v_pk_min_f16 %0, %1, %2" : "=v"(r) : "v"(a), "v"(b)); return r;
}
__device__ __forceinline__ unsigned pk_max(unsigned a, unsigned b) {
    unsigned r; asm("v_pk_max_f16 %0, %1, %2" : "=v"(r) : "v"(a), "v"(b)); return r;
}
__device__ __forceinline__ unsigned pk_add(unsigned a, unsigned b) {
    unsigned r; asm("v_pk_add_f16 %0, %1, %2" : "=v"(r) : "v"(a), "v"(b)); return r;
}
__device__ __forceinline__ unsigned pk_fma(unsigned a, unsigned b, unsigned c) {
    unsigned r; asm("v_pk_fma_f16 %0, %1, %2, %3" : "=v"(r) : "v"(a), "v"(b), "v"(c)); return r;
}
// {hi.low16, lo.high16}: result low half = lo's HIGH half, high half = hi's LOW half.
__device__ __forceinline__ unsigned alignb(unsigned hi, unsigned lo) {
    unsigned r; asm("v_alignbit_b32 %0, %1, %2, 16" : "=v"(r) : "v"(hi), "v"(lo)); return r;
}

union H2U { __half2 h; unsigned u; };

__device__ __forceinline__ uint2 ld2u(const __half* p) { return *(const uint2*)p; }
__device__ __forceinline__ void  st2u(__half* p, unsigned a, unsigned b) { *(uint2*)p = make_uint2(a, b); }
__device__ __forceinline__ void st4h(__half* p, float x, float y, float z, float w) {
    H2U a, b;
    a.h = __floats2half2_rn(x, y);
    b.h = __floats2half2_rn(z, w);
    *(uint2*)p = make_uint2(a.u, b.u);
}

// Overwrite region cells whose GLOBAL coords are outside the image with +INF
// (erode-input identity). b16 stores, consecutive addresses: conflict-free.
__device__ __forceinline__ void band_fix_inf(__half* b, int r0, int c0, int tid)
{
    unsigned short* u = (unsigned short*)b;
    const unsigned short val = 0x7C00;   // +inf f16
    if (r0 == 0) {
        for (int idx = tid; idx < HALO * RG; idx += 512) {
            const int r = idx / RG, c = idx - r * RG;
            u[r * HST + c] = val;
        }
    }
    if (r0 == H_IMG - TILE) {
        for (int idx = tid; idx < HALO * RG; idx += 512) {
            const int r = idx / RG, c = idx - r * RG;
            u[(RG - HALO + r) * HST + c] = val;
        }
    }
    if (c0 == 0) {
        for (int idx = tid; idx < RG * HALO; idx += 512) {
            const int r = idx / HALO, c = idx - r * HALO;
            u[r * HST + c] = val;
        }
    }
    if (c0 == W_IMG - TILE) {
        for (int idx = tid; idx < RG * HALO; idx += 512) {
            const int r = idx / HALO, c = idx - r * HALO;
            u[r * HST + (RG - HALO + c)] = val;
        }
    }
}

// ---------------------------------------------------------------------------
// f16 path (z<16): whole soft_skeleton of sigmoid(pred) for one 64x64 tile,
// packed-f16 math, fused BCE/dice + skel reductions.
// Bank design: b64 strip ops = 1 row x {16,8} consecutive strips per lane
// group (2-way, free); horizontal neighbors via __shfl + v_alignbit; strip-
// boundary lanes fall back to scalar u16 LDS reads (distinct rows -> banks).
// ---------------------------------------------------------------------------
template<bool SIG_SRC, bool SIG_OTH, bool DO_BCE, int CBASE>
__device__ __forceinline__
void skel_core(const float* __restrict__ src, const float* __restrict__ oth,
               double* __restrict__ acc, __half* cur, __half* nxt, float* red,
               int z, int r0, int c0, int tid, int bid)
{
    const float* s = src + (size_t)z * NPIX;

    // ---- load 88x88 region (+4-col pad), phase-aligned ----
    {   // phase A: strips 0..15, 1 row x 16 strips per quarter-wave
        const int st = tid & 15, c = 4 * st;
        const int gc = c0 - HALO + c;
        const bool vec = (gc >= 0) && (gc + 3 < W_IMG);
        for (int r = tid >> 4; r < RG; r += 32) {
            const int gr = min(max(r0 - HALO + r, 0), H_IMG - 1);
            const float* row = s + (size_t)gr * W_IMG;
            float4 v;
            if (vec) v = *(const float4*)&row[gc];
            else {
                v.x = row[min(max(gc + 0, 0), W_IMG - 1)];
                v.y = row[min(max(gc + 1, 0), W_IMG - 1)];
                v.z = row[min(max(gc + 2, 0), W_IMG - 1)];
                v.w = row[min(max(gc + 3, 0), W_IMG - 1)];
            }
            if (SIG_SRC) { v.x = sigm(v.x); v.y = sigm(v.y); v.z = sigm(v.z); v.w = sigm(v.w); }
            st4h(&cur[r * HST + c], v.x, v.y, v.z, v.w);
        }
    }
    {   // phase B: strips 16..22 (incl pad strip 22), 2 rows x 8 strips
        const int st = 16 + (tid & 7);
        if (st < 23) {
            const int c = 4 * st, gc = c0 - HALO + c;
            const bool vec = (gc >= 0) && (gc + 3 < W_IMG);
            for (int r = tid >> 3; r < RG; r += 64) {
                const int gr = min(max(r0 - HALO + r, 0), H_IMG - 1);
                const float* row = s + (size_t)gr * W_IMG;
                float4 v;
                if (vec) v = *(const float4*)&row[gc];
                else {
                    v.x = row[min(max(gc + 0, 0), W_IMG - 1)];
                    v.y = row[min(max(gc + 1, 0), W_IMG - 1)];
                    v.z = row[min(max(gc + 2, 0), W_IMG - 1)];
                    v.w = row[min(max(gc + 3, 0), W_IMG - 1)];
                }
                if (SIG_SRC) { v.x = sigm(v.x); v.y = sigm(v.y); v.z = sigm(v.z); v.w = sigm(v.w); }
                st4h(&cur[r * HST + c], v.x, v.y, v.z, v.w);
            }
        }
    }
    __syncthreads();

    const bool edge = (r0 == 0) | (c0 == 0) | (r0 == H_IMG - TILE) | (c0 == W_IMG - TILE);

    // packed skel accumulators: strips A,B x half2 pairs (01,23). f16 zero = 0.
    unsigned skA01 = 0, skA23 = 0, skB01 = 0, skB23 = 0;

    const int oy = tid >> 3;      // owned row 0..63
    const int j  = tid & 7;       // strip slot (strips j, j+8 of owned)
    const int rr = HALO + oy;

    for (int k = 0; k < 11; ++k) {
        if (edge) { band_fix_inf(cur, r0, c0, tid); __syncthreads(); }

        const int rlo = k + 1, rhi = RG - 1 - k;        // rows [rlo, rhi)
        const int sA = rlo >> 2, sE = (rhi + 3) >> 2;   // strips [sA, sE)

        // ---- erode phase A: strips sA..sA+15 (1 row x 16 strips/quarter) ----
        {
            const int l  = tid & 15;
            const int st = sA + l;
            const int c  = 4 * st;
            const int gcb = c0 - HALO + c;
            const bool cOOB = ((unsigned)gcb > (unsigned)(W_IMG - 4));
            for (int r = rlo + (tid >> 4); r < rhi; r += 32) {
                const int base = r * HST + c;
                const uint2 mid = ld2u(&cur[base]);
                const uint2 up  = ld2u(&cur[base - HST]);
                const uint2 dn  = ld2u(&cur[base + HST]);
                unsigned lfreg = (unsigned)__shfl_up((int)mid.y, 1);    // left strip m23
                unsigned rtreg = (unsigned)__shfl_down((int)mid.x, 1);  // right strip m01
                if (l == 0)  lfreg = ((unsigned)*(const unsigned short*)(cur + base - 1)) << 16;
                if (l == 15) rtreg = (unsigned)*(const unsigned short*)(cur + base + 4);
                const unsigned L01 = alignb(mid.x, lfreg);   // [m-1, m0]
                const unsigned L23 = alignb(mid.y, mid.x);   // [m1 , m2] (== R01)
                const unsigned R23 = alignb(rtreg, mid.y);   // [m3 , m4]
                unsigned e01 = pk_min(pk_min(pk_min(up.x, dn.x), mid.x), pk_min(L01, L23));
                unsigned e23 = pk_min(pk_min(pk_min(up.y, dn.y), mid.y), pk_min(L23, R23));
                if (edge) {
                    const int gr = r0 - HALO + r;
                    if (((unsigned)gr >= (unsigned)H_IMG) | cOOB) { e01 = PK_NINF; e23 = PK_NINF; }
                }
                st2u(&nxt[base], e01, e23);
            }
        }
        // ---- erode phase B: strips sA+16..sE-1 (2 rows x 8 strips/quarter) ----
        {
            const int l  = tid & 7;
            const int st = sA + 16 + l;
            if (st < sE) {   // sE-sA <= 22 -> l <= 6 active, shfl stays in-row
                const int c = 4 * st;
                const int gcb = c0 - HALO + c;
                const bool cOOB  = ((unsigned)gcb > (unsigned)(W_IMG - 4));
                const bool lastS = (st == sE - 1);
                for (int r = rlo + (tid >> 3); r < rhi; r += 64) {
                    const int base = r * HST + c;
                    const uint2 mid = ld2u(&cur[base]);
                    const uint2 up  = ld2u(&cur[base - HST]);
                    const uint2 dn  = ld2u(&cur[base + HST]);
                    unsigned lfreg = (unsigned)__shfl_up((int)mid.y, 1);
                    unsigned rtreg = (unsigned)__shfl_down((int)mid.x, 1);
                    if (l == 0)  lfreg = ((unsigned)*(const unsigned short*)(cur + base - 1)) << 16;
                    if (lastS)   rtreg = (unsigned)*(const unsigned short*)(cur + base + 4);
                    const unsigned L01 = alignb(mid.x, lfreg);
                    const unsigned L23 = alignb(mid.y, mid.x);
                    const unsigned R23 = alignb(rtreg, mid.y);
                    unsigned e01 = pk_min(pk_min(pk_min(up.x, dn.x), mid.x), pk_min(L01, L23));
                    unsigned e23 = pk_min(pk_min(pk_min(up.y, dn.y), mid.y), pk_min(L23, R23));
                    if (edge) {
                        const int gr = r0 - HALO + r;
                        if (((unsigned)gr >= (unsigned)H_IMG) | cOOB) { e01 = PK_NINF; e23 = PK_NINF; }
                    }
                    st2u(&nxt[base], e01, e23);
                }
            }
        }
        __syncthreads();

        // ---- dilate(ernew) at owned pixels + packed skel update ----
        {
            const int cA = HALO + 4 * j;           // strip j
            const int cB = cA + 32;                // strip j+8
            const int bA = rr * HST + cA;
            const int bB = rr * HST + cB;
            const uint2 a0 = ld2u(&nxt[bA - HST]);
            const uint2 m0 = ld2u(&nxt[bA]);
            const uint2 d0 = ld2u(&nxt[bA + HST]);
            const uint2 a1 = ld2u(&nxt[bB - HST]);
            const uint2 m1 = ld2u(&nxt[bB]);
            const uint2 d1 = ld2u(&nxt[bB + HST]);
            const unsigned VA01 = pk_max(pk_max(a0.x, m0.x), d0.x);
            const unsigned VA23 = pk_max(pk_max(a0.y, m0.y), d0.y);
            const unsigned VB01 = pk_max(pk_max(a1.x, m1.x), d1.x);
            const unsigned VB23 = pk_max(pk_max(a1.y, m1.y), d1.y);
            // horizontal neighbor regs (hi/lo halves used via alignb)
            unsigned vlA = (unsigned)__shfl_up((int)VA23, 1);        // high = V[cA-1]
            const unsigned vrAa = (unsigned)__shfl_down((int)VA01, 1);
            const unsigned vrAb = (unsigned)__shfl_up((int)VB01, 7); // j==7 seam: strip 8
            unsigned vrA = (j == 7) ? vrAb : vrAa;                   // low = V[cA+4]
            const unsigned vlBa = (unsigned)__shfl_up((int)VB23, 1);
            const unsigned vlBb = (unsigned)__shfl_down((int)VA23, 7); // j==0 seam: strip 7
            unsigned vlB = (j == 0) ? vlBb : vlBa;                   // high = V[cB-1]
            unsigned vrB = (unsigned)__shfl_down((int)VB01, 1);      // low = V[cB+4]
            if (j == 0) {   // block-left halo col: scalar u16 vertical max (low halves)
                const unsigned t1 = *(const unsigned short*)(nxt + bA - HST - 1);
                const unsigned t2 = *(const unsigned short*)(nxt + bA - 1);
                const unsigned t3 = *(const unsigned short*)(nxt + bA + HST - 1);
                vlA = pk_max(pk_max(t1, t2), t3) << 16;              // value -> high half
            }
            if (j == 7) {   // block-right halo col
                const unsigned t1 = *(const unsigned short*)(nxt + bB - HST + 4);
                const unsigned t2 = *(const unsigned short*)(nxt + bB + 4);
                const unsigned t3 = *(const unsigned short*)(nxt + bB + HST + 4);
                vrB = pk_max(pk_max(t1, t2), t3);                    // value in low half
            }
            // open = horizontal max3 of V (packed)
            const unsigned LA = alignb(VA01, vlA);    // [V-1, V0]
            const unsigned MA = alignb(VA23, VA01);   // [V1 , V2]
            const unsigned RA = alignb(vrA,  VA23);   // [V3 , V4]
            const unsigned oA01 = pk_max(pk_max(LA, MA), VA01);
            const unsigned oA23 = pk_max(pk_max(MA, RA), VA23);
            const unsigned LB = alignb(VB01, vlB);
            const unsigned MB = alignb(VB23, VB01);
            const unsigned RB = alignb(vrB,  VB23);
            const unsigned oB01 = pk_max(pk_max(LB, MB), VB01);
            const unsigned oB23 = pk_max(pk_max(MB, RB), VB23);
            // er_k at owned (pre-erode center values)
            const uint2 eA = ld2u(&cur[bA]);
            const uint2 eB = ld2u(&cur[bB]);
            // delta = relu(e - open); skel += relu(delta - skel*delta)
            unsigned d, u;
            d = pk_max(pk_add(eA.x, oA01 ^ PK_SGN), 0u);
            u = pk_max(pk_fma(skA01 ^ PK_SGN, d, d), 0u);
            skA01 = pk_add(skA01, u);
            d = pk_max(pk_add(eA.y, oA23 ^ PK_SGN), 0u);
            u = pk_max(pk_fma(skA23 ^ PK_SGN, d, d), 0u);
            skA23 = pk_add(skA23, u);
            d = pk_max(pk_add(eB.x, oB01 ^ PK_SGN), 0u);
            u = pk_max(pk_fma(skB01 ^ PK_SGN, d, d), 0u);
            skB01 = pk_add(skB01, u);
            d = pk_max(pk_add(eB.y, oB23 ^ PK_SGN), 0u);
            u = pk_max(pk_fma(skB23 ^ PK_SGN, d, d), 0u);
            skB23 = pk_add(skB23, u);
        }
        __syncthreads();

        __half* tp = cur; cur = nxt; nxt = tp;
    }

    // ---- unpack skel to f32 ----
    float skf[8];
    {
        H2U u; float2 f;
        u.u = skA01; f = __half22float2(u.h); skf[0] = f.x; skf[1] = f.y;
        u.u = skA23; f = __half22float2(u.h); skf[2] = f.x; skf[3] = f.y;
        u.u = skB01; f = __half22float2(u.h); skf[4] = f.x; skf[5] = f.y;
        u.u = skB23; f = __half22float2(u.h); skf[6] = f.x; skf[7] = f.y;
    }

    // ---- fused reductions over owned pixels ----
    const size_t gbase = (size_t)z * NPIX + (size_t)(r0 + oy) * W_IMG + c0;
    const float* op = oth + gbase;
    const float* pp = src + gbase;   // pred logits (DO_BCE only)
    float ss = 0.f, sso = 0.f, sb = 0.f, sp = 0.f, sy = 0.f, spy = 0.f;
    #pragma unroll
    for (int t = 0; t < 2; ++t) {
        const int cc = 4 * (j + 8 * t);
        float4 ov = *(const float4*)&op[cc];
        float o0 = ov.x, o1 = ov.y, o2 = ov.z, o3 = ov.w;
        if (SIG_OTH) { o0 = sigm(o0); o1 = sigm(o1); o2 = sigm(o2); o3 = sigm(o3); }
        const float s0 = skf[4*t], s1 = skf[4*t+1], s2 = skf[4*t+2], s3 = skf[4*t+3];
        ss  += s0 + s1 + s2 + s3;
        sso += s0 * o0 + s1 * o1 + s2 * o2 + s3 * o3;
        if (DO_BCE) {
            const float4 xv = *(const float4*)&pp[cc];
            const float xs[4] = {xv.x, xv.y, xv.z, xv.w};
            const float ys[4] = {o0, o1, o2, o3};   // SIG_OTH=false here: raw target
            #pragma unroll
            for (int q = 0; q < 4; ++q) {
                const float x = xs[q], y = ys[q];
                const float zz = __expf(-fabsf(x));
                const float inv = 1.0f / (1.0f + zz);
                sb += fmaxf(x, 0.f) + __logf(1.0f + zz) - y * x;
                const float p = (x >= 0.f) ? inv : zz * inv;
                sp += p; sy += y; spy += p * y;
            }
        }
    }
    for (int off = 32; off > 0; off >>= 1) {
        ss  += __shfl_down(ss,  off);
        sso += __shfl_down(sso, off);
        if (DO_BCE) {
            sb  += __shfl_down(sb,  off);
            sp  += __shfl_down(sp,  off);
            sy  += __shfl_down(sy,  off);
            spy += __shfl_down(spy, off);
        }
    }
    const int wid = tid >> 6, lane = tid & 63;
    if (lane == 0) {
        red[0 * 8 + wid] = ss;  red[1 * 8 + wid] = sso;
        if (DO_BCE) {
            red[2 * 8 + wid] = sb;  red[3 * 8 + wid] = sp;
            red[4 * 8 + wid] = sy;  red[5 * 8 + wid] = spy;
        }
    }
    __syncthreads();
    if (tid == 0) {
        double SS = 0, SO = 0, B0 = 0, B1 = 0, B2 = 0, B3 = 0;
        for (int w = 0; w < 8; ++w) {
            SS += (double)red[0 * 8 + w];  SO += (double)red[1 * 8 + w];
            if (DO_BCE) {
                B0 += (double)red[2 * 8 + w]; B1 += (double)red[3 * 8 + w];
                B2 += (double)red[4 * 8 + w]; B3 += (double)red[5 * 8 + w];
            }
        }
        const int slot = bid & (SLOTS - 1);
        atomicAdd(&acc[slot * 8 + CBASE],     SS);
        atomicAdd(&acc[slot * 8 + CBASE + 1], SO);
        if (DO_BCE) {
            atomicAdd(&acc[slot * 8 + 0], B0);
            atomicAdd(&acc[slot * 8 + 1], B1);
            atomicAdd(&acc[slot * 8 + 2], B2);
            atomicAdd(&acc[slot * 8 + 3], B3);
        }
    }
}

// ---------------------------------------------------------------------------
// Bool path (z>=16): EXACT bit-packed skeleton of the binary target.
// Region 88x88 bits; thread t<352 owns word w=t&3 (w<3 data) of row r=t>>2.
// Bit b of word w = region col 32w+b. Erode = AND over plus (funnel shifts +
// LDS vertical), dilate = OR over 3x3, skel |= er & ~open. Out-of-image cells:
// OR-in mask (=1, erode identity) on read; AND-out (=0, dilate identity) on
// erode output. Garbage at region margins confined exactly as in f16 path
// (erode-k output trusted at margin >= k+1; dilate ring needs margin 11).
// One barrier per iteration (ping-pong buffers, disjoint read/write sets).
// ---------------------------------------------------------------------------
__device__ __forceinline__
void bool_core(const float* __restrict__ tgt, const float* __restrict__ pred,
               double* __restrict__ acc, unsigned* bb, float* red,
               int z, int r0, int c0, int tid, int bid)
{
    unsigned* A  = bb;              // [RG*4]
    unsigned* B  = bb + RG * 4;
    unsigned* SK = bb + RG * 8;
    const float* tz = tgt + (size_t)z * NPIX;

    // ---- load + pack bits via wave ballot (row-major, 64+24 cols) ----
    {
        const int wv = tid >> 6, ln = tid & 63;
        for (int r = wv; r < RG; r += 8) {
            const int gr = min(max(r0 - HALO + r, 0), H_IMG - 1);
            const float* row = tz + (size_t)gr * W_IMG;
            const int gc = c0 - HALO + ln;
            const float v = row[min(max(gc, 0), W_IMG - 1)];
            const unsigned long long b0 = __ballot(v > 0.5f);
            float v2 = 0.f;
            if (ln < 24) v2 = row[min(max(gc + 64, 0), W_IMG - 1)];
            const unsigned long long b1 = __ballot((ln < 24) && (v2 > 0.5f));
            if (ln < 4) {
                const unsigned val = (ln == 0) ? (unsigned)b0
                                   : (ln == 1) ? (unsigned)(b0 >> 32)
                                   : (ln == 2) ? (unsigned)b1 : 0u;
                A[r * 4 + ln] = val;
            }
        }
    }
    __syncthreads();

    const int r = tid >> 2, w = tid & 3;
    const bool act = (tid < RG * 4);

    // out-of-image masks (1 = outside image)
    const int gcb = c0 - HALO + 32 * w;
    unsigned cm = 0;
    {
        const int lo = -gcb;                 // bits [0,lo) have gc<0
        if (lo > 0) cm |= (lo >= 32) ? 0xFFFFFFFFu : ((1u << lo) - 1u);
        const int hs = W_IMG - gcb;          // bits >= hs have gc>=W
        if (hs < 32) cm |= (hs <= 0) ? 0xFFFFFFFFu : ~((1u << hs) - 1u);
    }
    const int grs = r0 - HALO + r;
    const unsigned Mself = cm | ((((unsigned)grs)       >= (unsigned)H_IMG) ? 0xFFFFFFFFu : 0u);
    const unsigned Mup   = cm | ((((unsigned)(grs - 1)) >= (unsigned)H_IMG) ? 0xFFFFFFFFu : 0u);
    const unsigned Mdn   = cm | ((((unsigned)(grs + 1)) >= (unsigned)H_IMG) ? 0xFFFFFFFFu : 0u);
    const unsigned KILL  = ~Mself;

    const int iu = max(r - 1, 0) * 4 + w;
    const int id = min(r + 1, RG - 1) * 4 + w;

    unsigned mid  = act ? A[r * 4 + w] : 0u;
    unsigned skel = 0u;
    unsigned* sB = A; unsigned* dB = B;

    for (int k = 0; k < 11; ++k) {
        // erode (AND over plus shape)
        const unsigned me = mid | Mself;
        unsigned up = 0xFFFFFFFFu, dn = 0xFFFFFFFFu;
        if (act) { up = sB[iu] | Mup; dn = sB[id] | Mdn; }
        const unsigned pv = (unsigned)__shfl_up((int)me, 1);    // word w-1 (garbage at w==0: margin-0 col)
        const unsigned nx = (unsigned)__shfl_down((int)me, 1);  // word w+1
        const unsigned Lh = (me << 1) | (pv >> 31);
        const unsigned Rh = (me >> 1) | (nx << 31);
        const unsigned e  = (me & up & dn & Lh & Rh) & KILL;
        if (act) dB[r * 4 + w] = e;
        __syncthreads();
        // dilate (OR over 3x3) + skel |= er & ~open
        unsigned eu = 0, ed = 0;
        if (act) { eu = dB[iu]; ed = dB[id]; }
        const unsigned V  = e | eu | ed;
        const unsigned pV = (unsigned)__shfl_up((int)V, 1);
        const unsigned nV = (unsigned)__shfl_down((int)V, 1);
        const unsigned open = V | ((V << 1) | (pV >> 31)) | ((V >> 1) | (nV << 31));
        skel |= mid & ~open;
        mid = e;
        unsigned* tp = sB; sB = dB; dB = tp;
    }
    if (act) SK[r * 4 + w] = skel;
    __syncthreads();

    // ---- epilogue: ss = sum(skel bits), sso = sum(skel * sigmoid(pred)) ----
    const int oy = tid >> 3, j = tid & 7;
    const size_t gbase = (size_t)z * NPIX + (size_t)(r0 + oy) * W_IMG + c0;
    const float* pp = pred + gbase;
    float ss = 0.f, sso = 0.f;
    #pragma unroll
    for (int t = 0; t < 2; ++t) {
        const int cc  = 4 * (j + 8 * t);      // owned col offset (strip base)
        const int rcb = HALO + cc;            // region col (4-aligned, no word straddle)
        const unsigned wd = SK[(HALO + oy) * 4 + (rcb >> 5)] >> (rcb & 31);
        const float4 xv = *(const float4*)&pp[cc];
        const float p0 = sigm(xv.x), p1 = sigm(xv.y), p2 = sigm(xv.z), p3 = sigm(xv.w);
        const float b0 = (float)( wd       & 1u);
        const float b1 = (float)((wd >> 1) & 1u);
        const float b2 = (float)((wd >> 2) & 1u);
        const float b3 = (float)((wd >> 3) & 1u);
        ss  += b0 + b1 + b2 + b3;
        sso += b0 * p0 + b1 * p1 + b2 * p2 + b3 * p3;
    }
    for (int off = 32; off > 0; off >>= 1) {
        ss  += __shfl_down(ss,  off);
        sso += __shfl_down(sso, off);
    }
    const int wid = tid >> 6, lane = tid & 63;
    if (lane == 0) { red[0 * 8 + wid] = ss; red[1 * 8 + wid] = sso; }
    __syncthreads();
    if (tid == 0) {
        double SS = 0, SO = 0;
        for (int wq = 0; wq < 8; ++wq) { SS += (double)red[0 * 8 + wq]; SO += (double)red[1 * 8 + wq]; }
        const int slot = bid & (SLOTS - 1);
        atomicAdd(&acc[slot * 8 + 6], SS);
        atomicAdd(&acc[slot * 8 + 7], SO);
    }
}

// Both skeletons in one dispatch: z<16 -> f16 skel(sigmoid(pred)) + BCE/dice;
// z>=16 -> exact bit-packed skel(target), reduced against sigmoid(pred).
__global__ __launch_bounds__(512, 8)
void skel_all(const float* __restrict__ pred, const float* __restrict__ tgt,
              double* __restrict__ acc)
{
    __shared__ __align__(16) __half buf0[RG * HST];
    __shared__ __align__(16) __half buf1[RG * HST];
    __shared__ float red[48];
    const int tid = threadIdx.x;
    const int r0 = blockIdx.y * TILE, c0 = blockIdx.x * TILE;
    const int bid = ((int)blockIdx.z & 15) * 256 + blockIdx.y * 16 + blockIdx.x;
    if ((int)blockIdx.z < N_B)
        skel_core<true, false, true, 4>(pred, tgt, acc, buf0, buf1, red,
                                        blockIdx.z, r0, c0, tid, bid);
    else
        bool_core(tgt, pred, acc, (unsigned*)buf0, red,
                  (int)blockIdx.z - N_B, r0, c0, tid, bid);
}

__global__ void zero_acc(double* acc) { acc[threadIdx.x] = 0.0; }

__global__ void finalize_k(const double* __restrict__ acc, float* __restrict__ out)
{
    __shared__ double S[8];
    const int jj = threadIdx.x;
    if (jj < 8) {
        double t = 0.0;
        for (int s = 0; s < SLOTS; ++s) t += acc[s * 8 + jj];
        S[jj] = t;
    }
    __syncthreads();
    if (jj == 0) {
        const double bce   = S[0] / (double)N_TOT;
        const double dice  = (2.0 * S[3] + 1.0) / (S[1] + S[2] + 1.0);
        const double tprec = (S[5] + 1.0) / (S[4] + 1.0);
        const double tsens = (S[7] + 1.0) / (S[6] + 1.0);
        const double cl    = 2.0 * tprec * tsens / (tprec + tsens + 1e-7);
        out[0] = (float)(0.3 * bce + 0.3 * (1.0 - dice) + 0.4 * (1.0 - cl));
    }
}

// ---------------------------------------------------------------------------
extern "C" void kernel_launch(void* const* d_in, const int* in_sizes, int n_in,
                              void* d_out, int out_size, void* d_ws, size_t ws_size,
                              hipStream_t stream)
{
    const float* pred = (const float*)d_in[0];
    const float* tgt  = (const float*)d_in[1];
    float* out = (float*)d_out;
    double* acc = (double*)d_ws;                  // SLOTS*8 doubles = 2 KB

    zero_acc<<<1, SLOTS * 8, 0, stream>>>(acc);

    const dim3 grid(W_IMG / TILE, H_IMG / TILE, 2 * N_B);   // (16,16,32)
    skel_all<<<grid, 512, 0, stream>>>(pred, tgt, acc);

    finalize_k<<<1, 64, 0, stream>>>(acc, out);
}